// Round 1
// baseline (1319.925 us; speedup 1.0000x reference)
//
#include <hip/hip_runtime.h>

#define G   160
#define G3  (G*G*G)          // 4,096,000
#define NV  300000
#define EPS 1e-4f

typedef unsigned short u16;
typedef __attribute__((ext_vector_type(8))) short bf16x8;
typedef __attribute__((ext_vector_type(4))) float f32x4;

// ---- workspace layout (bytes) ----
// R3: atomic scatter eliminated -> output-stationary gather over full [27][N]
// neighbor table. No pair lists / counts / CAP anymore.
#define OFF_GRID 0ull                        // G3*4        = 16,384,000
#define OFF_NBR  16384000ull                 // 27*NV*4     = 32,400,000
#define OFF_H0   (OFF_NBR  + 32400000ull)    // NV*64*2     = 38,400,000
#define OFF_H1   (OFF_H0   + 38400000ull)    // NV*128*2    = 76,800,000
#define OFF_W1T  (OFF_H1   + 76800000ull)    // 27*128*64*2 (B^T layout [k][cout][cin])
#define OFF_W2T  (OFF_W1T  + 442368ull)      // 27*128*128*2
#define OFF_LINW (OFF_W2T  + 884736ull)      // 128*64*2
#define WS_NEED  (OFF_LINW + 16384ull)       // ~165.3 MB (prev build used 200.4 MB ok)

__device__ __forceinline__ u16 f2bf(float f) {   // fp32 -> bf16 RNE
  unsigned u = __float_as_uint(f);
  return (u16)((u + 0x7fffu + ((u >> 16) & 1u)) >> 16);
}

// ---------- phase 1: hash grid + full neighbor table ----------
__global__ void k_grid(const int* __restrict__ pos, int* __restrict__ grid) {
  int i = blockIdx.x * 256 + threadIdx.x;
  if (i < NV)
    grid[(pos[3*i] * G + pos[3*i+1]) * G + pos[3*i+2]] = i;
}

// nbr[k][i] = input row feeding output i at tap k (-1 if empty). Tap 13 is the
// self tap: grid[flat(pos[i])] == i, so no special case. 27 loads in flight.
__global__ void k_nbr(const int* __restrict__ pos, const int* __restrict__ grid,
                      int* __restrict__ nbr) {
  int i = blockIdx.x * 256 + threadIdx.x;
  if (i >= NV) return;
  int p0 = pos[3*i], p1 = pos[3*i+1], p2 = pos[3*i+2];
  #pragma unroll
  for (int k = 0; k < 27; ++k) {
    int q0 = p0 + k/9 - 1, q1 = p1 + (k/3)%3 - 1, q2 = p2 + k%3 - 1;
    bool inb = (q0 >= 0 && q0 < G && q1 >= 0 && q1 < G && q2 >= 0 && q2 < G);
    int addr = inb ? (q0*G + q1)*G + q2 : 0;     // clamped: unconditional load
    int j = grid[addr];
    nbr[k * NV + i] = inb ? j : -1;
  }
}

// ---------- phase 2: BN1+ReLU -> bf16 h0 ; weight cast/transpose ----------
__global__ void k_bn1(const float* __restrict__ feat, const float* g, const float* b,
                      const float* m, const float* v, u16* __restrict__ h0) {
  __shared__ float ss[64], tt[64];
  int t = threadIdx.x;
  if (t < 64) { float s = g[t] * rsqrtf(v[t] + EPS); ss[t] = s; tt[t] = b[t] - m[t]*s; }
  __syncthreads();
  long gt = (long)blockIdx.x * 256 + t;            // one thread per 4 elems
  if (gt >= (long)NV * 16) return;
  int c = (int)(gt & 15) * 4;
  float4 x = ((const float4*)feat)[gt];
  ushort4 q;
  q.x = f2bf(fmaxf(x.x*ss[c  ] + tt[c  ], 0.f));
  q.y = f2bf(fmaxf(x.y*ss[c+1] + tt[c+1], 0.f));
  q.z = f2bf(fmaxf(x.z*ss[c+2] + tt[c+2], 0.f));
  q.w = f2bf(fmaxf(x.w*ss[c+3] + tt[c+3], 0.f));
  ((ushort4*)h0)[gt] = q;
}

// W -> bf16, transposed to [k][cout][cin] so MFMA B-frags are k-contiguous.
__global__ void k_weights(const float* __restrict__ W1, const float* __restrict__ W2,
                          const float* __restrict__ linw,
                          u16* __restrict__ w1t, u16* __restrict__ w2t, u16* __restrict__ lwt) {
  __shared__ float tmp[8192];
  int b = blockIdx.x, t = threadIdx.x;
  if (b < 27) {                                    // W1[k]: [64][128] -> [128][64]
    const float* src = W1 + b * 8192;
    u16* dst = w1t + b * 8192;
    for (int u = t; u < 8192; u += 256) tmp[u] = src[u];
    __syncthreads();
    for (int u = t; u < 8192; u += 256) { int c = u >> 6, a = u & 63; dst[c*64 + a] = f2bf(tmp[a*128 + c]); }
  } else if (b < 54) {                             // W2[k]: [128][128] -> [128][128]^T, two halves
    int k = b - 27;
    const float* src = W2 + k * 16384;
    u16* dst = w2t + k * 16384;
    for (int h = 0; h < 2; h++) {
      for (int u = t; u < 8192; u += 256) tmp[u] = src[h*8192 + u];
      __syncthreads();
      for (int u = t; u < 8192; u += 256) { int c = u >> 6, a = u & 63; dst[c*128 + h*64 + a] = f2bf(tmp[a*128 + c]); }
      __syncthreads();
    }
  } else {                                         // lin_w [128][64] is already B^T layout
    for (int u = t; u < 8192; u += 256) lwt[u] = f2bf(linw[u]);
  }
}

// ---------- GEMM building blocks (128x128 tile, 4 waves, 64x64 quadrants) ----------
template<int K, int RS>   // K: reduce dim; RS: global row stride (bf16 elems)
__device__ __forceinline__ void stage_rows(const u16* __restrict__ src, const int* sidx, u16* lds) {
  const int LPR = K / 8, RPI = 256 / LPR;          // 16B loaders per row, rows per iter
  int t = threadIdx.x, o = t % LPR, r0 = t / LPR;
  #pragma unroll
  for (int r = r0; r < 128; r += RPI) {
    int j = sidx[r];
    int4 val = make_int4(0, 0, 0, 0);
    if (j >= 0) val = *(const int4*)(src + (long)j * RS + o * 8);
    *(int4*)(lds + r * (K + 8) + o * 8) = val;     // +8 elem pad: low-order LDS banking
  }
}

__device__ __forceinline__ void stage_feat(const float* __restrict__ feat, int row0, u16* lds) {
  int t = threadIdx.x, o = t & 15, r0 = t >> 4;    // fp32->bf16 on the fly, K=64
  #pragma unroll
  for (int r = r0; r < 128; r += 16) {
    int row = row0 + r;
    float4 x = make_float4(0.f, 0.f, 0.f, 0.f);
    if (row < NV) x = *(const float4*)(feat + (long)row * 64 + o * 4);
    ushort4 q; q.x = f2bf(x.x); q.y = f2bf(x.y); q.z = f2bf(x.z); q.w = f2bf(x.w);
    *(ushort4*)(lds + r * 72 + o * 4) = q;
  }
}

template<int K>           // A from padded LDS; B-frags straight from L2-hot transposed weights
__device__ __forceinline__ void mma_tile(const u16* As, const u16* __restrict__ wt, f32x4 acc[4][4]) {
  int lane = threadIdx.x & 63, wave = threadIdx.x >> 6;
  int wr = (wave >> 1) * 64, wc = (wave & 1) * 64;
  int lr = lane & 15, lk = (lane >> 4) * 8;
  #pragma unroll
  for (int kk = 0; kk < K; kk += 32) {
    bf16x8 a[4], b[4];
    #pragma unroll
    for (int f = 0; f < 4; f++) a[f] = *(const bf16x8*)(As + (wr + f*16 + lr) * (K + 8) + kk + lk);
    #pragma unroll
    for (int f = 0; f < 4; f++) b[f] = *(const bf16x8*)(wt + (wc + f*16 + lr) * K + kk + lk);
    #pragma unroll
    for (int fr = 0; fr < 4; fr++)
      #pragma unroll
      for (int fc = 0; fc < 4; fc++)
        acc[fr][fc] = __builtin_amdgcn_mfma_f32_16x16x32_bf16(a[fr], b[fc], acc[fr][fc], 0, 0, 0);
  }
}

// ---------- conv1: output-stationary gather over 27 taps, fused BN2+ReLU -> bf16 h1 ----------
// Block owns 128 output rows; all taps accumulate in registers; zero atomics.
// nbr indices prefetched one tap ahead to hide the 512B coalesced load latency.
__global__ __launch_bounds__(256, 4) void k_conv1(const u16* __restrict__ h0,
                                                  const u16* __restrict__ w1t,
                                                  const int* __restrict__ nbr,
                                                  const float* g, const float* b,
                                                  const float* m, const float* v,
                                                  u16* __restrict__ h1) {
  __shared__ __align__(16) u16 As[128 * 136];      // stage: [128][72]; epilogue: [128][136]
  __shared__ int sidx[128];
  __shared__ float ss[128], tt[128];
  int t = threadIdx.x, row0 = blockIdx.x * 128;
  if (t < 128) { float s = g[t] * rsqrtf(v[t] + EPS); ss[t] = s; tt[t] = b[t] - m[t]*s; }
  int nb = -1;
  if (t < 128 && row0 + t < NV) nb = nbr[row0 + t];            // tap 0
  f32x4 acc[4][4] = {};
  for (int k = 0; k < 27; ++k) {
    if (t < 128) sidx[t] = nb;
    __syncthreads();                               // prev mma done (As free) + sidx visible
    if (t < 128) nb = (k < 26 && row0 + t < NV) ? nbr[(k + 1) * NV + row0 + t] : -1;
    stage_rows<64, 64>(h0, sidx, As);
    __syncthreads();
    mma_tile<64>(As, w1t + k * 8192, acc);
  }
  __syncthreads();                                 // all mma done; reuse As as bf16 [128][136]
  int lane = t & 63, wave = t >> 6;
  int wr = (wave >> 1) * 64, wc = (wave & 1) * 64, cr = (lane >> 4) * 4, cc = lane & 15;
  #pragma unroll
  for (int fr = 0; fr < 4; fr++)
    #pragma unroll
    for (int r = 0; r < 4; r++) {
      int rr = wr + fr*16 + cr + r;
      #pragma unroll
      for (int fc = 0; fc < 4; fc++) {
        int col = wc + fc*16 + cc;
        As[rr * 136 + col] = f2bf(fmaxf(acc[fr][fc][r] * ss[col] + tt[col], 0.f));
      }
    }
  __syncthreads();
  #pragma unroll
  for (int u = t; u < 2048; u += 256) {            // coalesced 256B-row copy-out
    int r = u >> 4, o = u & 15, row = row0 + r;
    if (row < NV) *(int4*)(h1 + (long)row * 128 + o * 8) = *(const int4*)(As + r * 136 + o * 8);
  }
}

// ---------- conv2: NiN skip (feat@lin_w^T) prologue + 27 gather taps, write out once ----------
__global__ __launch_bounds__(256, 4) void k_conv2(const float* __restrict__ feat,
                                                  const u16* __restrict__ lwt,
                                                  const u16* __restrict__ h1,
                                                  const u16* __restrict__ w2t,
                                                  const int* __restrict__ nbr,
                                                  float* __restrict__ out) {
  __shared__ __align__(16) u16 As[128 * 136];
  __shared__ int sidx[128];
  int t = threadIdx.x, row0 = blockIdx.x * 128;
  int nb = -1;
  if (t < 128 && row0 + t < NV) nb = nbr[row0 + t];
  f32x4 acc[4][4] = {};
  stage_feat(feat, row0, As);                      // K=64 NiN pass (stride 72 region)
  __syncthreads();
  mma_tile<64>(As, lwt, acc);
  for (int k = 0; k < 27; ++k) {
    if (t < 128) sidx[t] = nb;
    __syncthreads();                               // prev mma done + sidx visible
    if (t < 128) nb = (k < 26 && row0 + t < NV) ? nbr[(k + 1) * NV + row0 + t] : -1;
    stage_rows<128, 128>(h1, sidx, As);            // h1 dense: row stride 128 elems
    __syncthreads();
    mma_tile<128>(As, w2t + k * 16384, acc);
  }
  int lane = t & 63, wave = t >> 6;
  int wr = (wave >> 1) * 64, wc = (wave & 1) * 64, cr = (lane >> 4) * 4, cc = lane & 15;
  #pragma unroll
  for (int fr = 0; fr < 4; fr++)
    #pragma unroll
    for (int r = 0; r < 4; r++) {
      int row = row0 + wr + fr*16 + cr + r;
      if (row >= NV) continue;
      #pragma unroll
      for (int fc = 0; fc < 4; fc++)
        out[(long)row * 128 + wc + fc*16 + cc] = acc[fr][fc][r];
    }
}

extern "C" void kernel_launch(void* const* d_in, const int* in_sizes, int n_in,
                              void* d_out, int out_size, void* d_ws, size_t ws_size,
                              hipStream_t stream) {
  const float* feat = (const float*)d_in[0];
  const int*   pos  = (const int*)d_in[1];
  const float* linw = (const float*)d_in[2];
  const float* g1 = (const float*)d_in[3], *b1 = (const float*)d_in[4];
  const float* m1 = (const float*)d_in[5], *v1 = (const float*)d_in[6];
  const float* W1 = (const float*)d_in[7];
  const float* g2 = (const float*)d_in[8], *b2 = (const float*)d_in[9];
  const float* m2 = (const float*)d_in[10], *v2 = (const float*)d_in[11];
  const float* W2 = (const float*)d_in[12];

  if (ws_size < WS_NEED) return;  // insufficient scratch; fail visibly rather than corrupt

  char* ws = (char*)d_ws;
  int*   grid = (int*)(ws + OFF_GRID);
  int*   nbr  = (int*)(ws + OFF_NBR);
  u16*   h0   = (u16*)(ws + OFF_H0);
  u16*   h1   = (u16*)(ws + OFF_H1);
  u16*   w1t  = (u16*)(ws + OFF_W1T);
  u16*   w2t  = (u16*)(ws + OFF_W2T);
  u16*   lwt  = (u16*)(ws + OFF_LINW);
  float* out  = (float*)d_out;

  hipMemsetAsync(grid, 0xFF, (size_t)G3 * 4, stream);       // grid = -1

  k_grid <<<(NV + 255) / 256, 256, 0, stream>>>(pos, grid);
  k_nbr  <<<(NV + 255) / 256, 256, 0, stream>>>(pos, grid, nbr);
  k_bn1  <<<(NV * 16) / 256, 256, 0, stream>>>(feat, g1, b1, m1, v1, h0);
  k_weights<<<55, 256, 0, stream>>>(W1, W2, linw, w1t, w2t, lwt);

  dim3 gt((NV + 127) / 128);
  k_conv1<<<gt, 256, 0, stream>>>(h0, w1t, nbr, g2, b2, m2, v2, h1);
  k_conv2<<<gt, 256, 0, stream>>>(feat, lwt, h1, w2t, nbr, out);
}

// Round 2
// 900.031 us; speedup vs baseline: 1.4665x; 1.4665x over previous
//
#include <hip/hip_runtime.h>

#define G    160
#define G3   (G*G*G)          // 4,096,000
#define NV   300000
#define EPS  1e-4f
#define CAP  24576            // per-tap pair capacity (expected ~22.0k, +18 sigma)
#define CPAD 32               // counts[k] lives at counts[k*CPAD]: one 128B line per counter

typedef unsigned short u16;
typedef __attribute__((ext_vector_type(8))) short bf16x8;
typedef __attribute__((ext_vector_type(4))) float f32x4;

// ---- workspace layout (bytes) ----
// R4: back to per-tap pair-list gather-GEMM (R2 structure) but atomics replaced by
// bf16 partial rows + inverse map pslot[k][i] + fused self-GEMM reduce kernels.
// partial overlays grid (grid dead after k_pairs, partials written later).
#define OFF_PART 0ull                          // 27*CAP*128*2 = 169,869,312
#define OFF_GRID 0ull                          // 16,384,000 (dies before partial writes)
#define OFF_PIN  169869312ull                  // 27*CAP*4 = 2,654,208
#define OFF_PSL  (OFF_PIN + 2654208ull)        // 27*NV*4  = 32,400,000
#define OFF_CNT  (OFF_PSL + 32400000ull)       // 4096
#define OFF_H0   (OFF_CNT + 4096ull)           // NV*64*2  = 38,400,000
#define OFF_H1   (OFF_H0  + 38400000ull)       // NV*128*2 = 76,800,000
#define OFF_W1T  (OFF_H1  + 76800000ull)       // 27*128*64*2  (B^T layout [k][cout][cin])
#define OFF_W2T  (OFF_W1T + 442368ull)         // 27*128*128*2
#define OFF_LINW (OFF_W2T + 884736ull)         // 128*64*2
#define WS_NEED  (OFF_LINW + 16384ull)         // ~321.5 MB

__device__ __forceinline__ u16 f2bf(float f) {   // fp32 -> bf16 RNE
  unsigned u = __float_as_uint(f);
  return (u16)((u + 0x7fffu + ((u >> 16) & 1u)) >> 16);
}
__device__ __forceinline__ float bf2f(u16 h) {
  return __uint_as_float(((unsigned)h) << 16);
}

// ---------- phase 1: hash grid + per-tap pair lists + inverse slot map ----------
__global__ void k_grid(const int* __restrict__ pos, int* __restrict__ grid) {
  int i = blockIdx.x * 256 + threadIdx.x;
  if (i < NV)
    grid[(pos[3*i] * G + pos[3*i+1]) * G + pos[3*i+2]] = i;
}

// LDS-hierarchical slot allocation (R2-proven: 1 global atomic per block per tap,
// counters padded to separate L2 lines). Additionally writes pslot[k*NV+i] = slot
// so the reduce kernels can gather partials without atomics.
__global__ __launch_bounds__(256) void k_pairs(const int* __restrict__ pos,
                        const int* __restrict__ grid,
                        int* __restrict__ pin, int* __restrict__ pslot,
                        int* __restrict__ counts) {
  __shared__ int lcnt[27];
  __shared__ int wboff[27][4];
  __shared__ int gbase[27];
  int t = threadIdx.x, lane = t & 63, wv = t >> 6;
  if (t < 27) lcnt[t] = 0;
  int i = blockIdx.x * 256 + t;
  bool act = (i < NV);
  int p0 = 0, p1 = 1 << 20, p2 = 0;              // inactive threads -> always OOB
  if (act) { p0 = pos[3*i]; p1 = pos[3*i+1]; p2 = pos[3*i+2]; }
  __syncthreads();                               // lcnt zeroed

  int j[26];
  #pragma unroll
  for (int kk = 0; kk < 26; kk++) {              // all 26 loads independent & in flight
    int k = kk < 13 ? kk : kk + 1;
    int q0 = p0 + k/9 - 1, q1 = p1 + (k/3)%3 - 1, q2 = p2 + k%3 - 1;
    bool inb = (q0 >= 0 && q0 < G && q1 >= 0 && q1 < G && q2 >= 0 && q2 < G);
    int addr = inb ? (q0*G + q1)*G + q2 : 0;     // clamped: unconditional load
    int jj = grid[addr];
    j[kk] = inb ? jj : -1;
  }

  unsigned long long m[26];                      // wave-uniform -> SGPRs
  #pragma unroll
  for (int kk = 0; kk < 26; kk++) m[kk] = __ballot(j[kk] >= 0);

  #pragma unroll
  for (int kk = 0; kk < 26; kk++) {              // per-block aggregation in LDS
    int k = kk < 13 ? kk : kk + 1;
    if (lane == 0) wboff[k][wv] = atomicAdd(&lcnt[k], (int)__popcll(m[kk]));
  }
  __syncthreads();
  if (t < 27 && t != 13)                         // 27 concurrent atomics, separate L2 lines
    gbase[t] = atomicAdd(&counts[t * CPAD], lcnt[t]);
  __syncthreads();

  #pragma unroll
  for (int kk = 0; kk < 26; kk++) {
    if (j[kk] >= 0) {
      int k = kk < 13 ? kk : kk + 1;
      int slot = gbase[k] + wboff[k][wv] + (int)__popcll(m[kk] & ((1ull << lane) - 1ull));
      if (slot < CAP) {
        pin[k*CAP + slot] = j[kk];
        pslot[k*NV + i] = slot;
      }
    }
  }
}

// ---------- phase 2: BN1+ReLU -> bf16 h0 ; weight cast/transpose ----------
__global__ void k_bn1(const float* __restrict__ feat, const float* g, const float* b,
                      const float* m, const float* v, u16* __restrict__ h0) {
  __shared__ float ss[64], tt[64];
  int t = threadIdx.x;
  if (t < 64) { float s = g[t] * rsqrtf(v[t] + EPS); ss[t] = s; tt[t] = b[t] - m[t]*s; }
  __syncthreads();
  long gt = (long)blockIdx.x * 256 + t;            // one thread per 4 elems
  if (gt >= (long)NV * 16) return;
  int c = (int)(gt & 15) * 4;
  float4 x = ((const float4*)feat)[gt];
  ushort4 q;
  q.x = f2bf(fmaxf(x.x*ss[c  ] + tt[c  ], 0.f));
  q.y = f2bf(fmaxf(x.y*ss[c+1] + tt[c+1], 0.f));
  q.z = f2bf(fmaxf(x.z*ss[c+2] + tt[c+2], 0.f));
  q.w = f2bf(fmaxf(x.w*ss[c+3] + tt[c+3], 0.f));
  ((ushort4*)h0)[gt] = q;
}

// W -> bf16, transposed to [k][cout][cin] so MFMA B-frags are k-contiguous.
__global__ void k_weights(const float* __restrict__ W1, const float* __restrict__ W2,
                          const float* __restrict__ linw,
                          u16* __restrict__ w1t, u16* __restrict__ w2t, u16* __restrict__ lwt) {
  __shared__ float tmp[8192];
  int b = blockIdx.x, t = threadIdx.x;
  if (b < 27) {                                    // W1[k]: [64][128] -> [128][64]
    const float* src = W1 + b * 8192;
    u16* dst = w1t + b * 8192;
    for (int u = t; u < 8192; u += 256) tmp[u] = src[u];
    __syncthreads();
    for (int u = t; u < 8192; u += 256) { int c = u >> 6, a = u & 63; dst[c*64 + a] = f2bf(tmp[a*128 + c]); }
  } else if (b < 54) {                             // W2[k]: [128][128] -> [128][128]^T, two halves
    int k = b - 27;
    const float* src = W2 + k * 16384;
    u16* dst = w2t + k * 16384;
    for (int h = 0; h < 2; h++) {
      for (int u = t; u < 8192; u += 256) tmp[u] = src[h*8192 + u];
      __syncthreads();
      for (int u = t; u < 8192; u += 256) { int c = u >> 6, a = u & 63; dst[c*128 + h*64 + a] = f2bf(tmp[a*128 + c]); }
      __syncthreads();
    }
  } else {                                         // lin_w [128][64] is already B^T layout
    for (int u = t; u < 8192; u += 256) lwt[u] = f2bf(linw[u]);
  }
}

// ---------- GEMM building blocks (128x128 tile, 4 waves, 64x64 quadrants) ----------
template<int K, int RS>   // K: reduce dim; RS: global row stride (bf16 elems)
__device__ __forceinline__ void stage_rows(const u16* __restrict__ src, const int* sidx, u16* lds) {
  const int LPR = K / 8, RPI = 256 / LPR;          // 16B loaders per row, rows per iter
  int t = threadIdx.x, o = t % LPR, r0 = t / LPR;
  #pragma unroll
  for (int r = r0; r < 128; r += RPI) {
    int j = sidx[r];
    int4 val = make_int4(0, 0, 0, 0);
    if (j >= 0) val = *(const int4*)(src + (long)j * RS + o * 8);
    *(int4*)(lds + r * (K + 8) + o * 8) = val;     // +8 elem pad: low-order LDS banking
  }
}

__device__ __forceinline__ void stage_feat(const float* __restrict__ feat, int row0, u16* lds) {
  int t = threadIdx.x, o = t & 15, r0 = t >> 4;    // fp32->bf16 on the fly, K=64
  #pragma unroll
  for (int r = r0; r < 128; r += 16) {
    int row = row0 + r;
    float4 x = make_float4(0.f, 0.f, 0.f, 0.f);
    if (row < NV) x = *(const float4*)(feat + (long)row * 64 + o * 4);
    ushort4 q; q.x = f2bf(x.x); q.y = f2bf(x.y); q.z = f2bf(x.z); q.w = f2bf(x.w);
    *(ushort4*)(lds + r * 72 + o * 4) = q;
  }
}

template<int K>           // A from padded LDS; B-frags straight from L2-hot transposed weights
__device__ __forceinline__ void mma_tile(const u16* As, const u16* __restrict__ wt, f32x4 acc[4][4]) {
  int lane = threadIdx.x & 63, wave = threadIdx.x >> 6;
  int wr = (wave >> 1) * 64, wc = (wave & 1) * 64;
  int lr = lane & 15, lk = (lane >> 4) * 8;
  #pragma unroll
  for (int kk = 0; kk < K; kk += 32) {
    bf16x8 a[4], b[4];
    #pragma unroll
    for (int f = 0; f < 4; f++) a[f] = *(const bf16x8*)(As + (wr + f*16 + lr) * (K + 8) + kk + lk);
    #pragma unroll
    for (int f = 0; f < 4; f++) b[f] = *(const bf16x8*)(wt + (wc + f*16 + lr) * K + kk + lk);
    #pragma unroll
    for (int fr = 0; fr < 4; fr++)
      #pragma unroll
      for (int fc = 0; fc < 4; fc++)
        acc[fr][fc] = __builtin_amdgcn_mfma_f32_16x16x32_bf16(a[fr], b[fc], acc[fr][fc], 0, 0, 0);
  }
}

// ---------- non-self taps: gather-GEMM -> bf16 partial rows (plain stores, no atomics) ----------
template<int K, int RS>
__global__ __launch_bounds__(256) void k_scat(const u16* __restrict__ h, const u16* __restrict__ wt,
                                              const int* __restrict__ pin,
                                              const int* __restrict__ counts,
                                              u16* __restrict__ partial) {
  int k = blockIdx.y;
  int cnt = counts[k * CPAD]; if (cnt > CAP) cnt = CAP;
  int base = blockIdx.x * 128;
  if (base >= cnt) return;                         // k==13 (cnt 0) and tail tiles exit here
  __shared__ __align__(16) u16 As[128 * 136];      // stage: [128][K+8]; epilogue: [128][136]
  __shared__ int sin[128];
  int t = threadIdx.x;
  if (t < 128) sin[t] = (base + t < cnt) ? pin[k*CAP + base + t] : -1;
  __syncthreads();
  stage_rows<K, RS>(h, sin, As);
  __syncthreads();
  f32x4 acc[4][4] = {};
  mma_tile<K>(As, wt + k * (K * 128), acc);
  __syncthreads();                                 // As free; reuse as bf16 [128][136]
  int lane = t & 63, wave = t >> 6;
  int wr = (wave >> 1) * 64, wc = (wave & 1) * 64, cr = (lane >> 4) * 4, cc = lane & 15;
  #pragma unroll
  for (int fr = 0; fr < 4; fr++)
    #pragma unroll
    for (int r = 0; r < 4; r++)
      #pragma unroll
      for (int fc = 0; fc < 4; fc++)
        As[(wr + fr*16 + cr + r) * 136 + wc + fc*16 + cc] = f2bf(acc[fr][fc][r]);
  __syncthreads();
  #pragma unroll
  for (int u = t; u < 2048; u += 256) {            // coalesced 256B-row copy-out
    int r = u >> 4, o = u & 15;
    if (base + r < cnt)
      *(int4*)(partial + ((long)k*CAP + base + r) * 128 + o * 8) = *(const int4*)(As + r * 136 + o * 8);
  }
}

// ---------- conv1 reduce: self GEMM + partial gather-sum + BN2+ReLU -> bf16 h1 ----------
__global__ __launch_bounds__(256, 2) void k_reduce1(const u16* __restrict__ h0,
                                                    const u16* __restrict__ w1t,
                                                    const int* __restrict__ pslot,
                                                    const u16* __restrict__ partial,
                                                    const float* g, const float* b,
                                                    const float* m, const float* v,
                                                    u16* __restrict__ h1) {
  __shared__ __align__(16) char smem[128 * 132 * 4];  // union: As [128][72] u16 | accum [128][132] f32
  __shared__ float ss[128], tt[128];
  __shared__ int sidx[128];
  u16*   As    = (u16*)smem;
  float* accum = (float*)smem;
  int t = threadIdx.x, row0 = blockIdx.x * 128;
  if (t < 128) {
    float s = g[t] * rsqrtf(v[t] + EPS); ss[t] = s; tt[t] = b[t] - m[t]*s;
    sidx[t] = (row0 + t < NV) ? row0 + t : -1;
  }
  __syncthreads();
  stage_rows<64, 64>(h0, sidx, As);
  __syncthreads();
  f32x4 acc[4][4] = {};
  mma_tile<64>(As, w1t + 13 * 8192, acc);
  __syncthreads();                                 // As dead -> accum
  int lane = t & 63, wave = t >> 6;
  int wr = (wave >> 1) * 64, wc = (wave & 1) * 64, cr = (lane >> 4) * 4, cc = lane & 15;
  #pragma unroll
  for (int fr = 0; fr < 4; fr++)
    #pragma unroll
    for (int r = 0; r < 4; r++)
      #pragma unroll
      for (int fc = 0; fc < 4; fc++)
        accum[(wr + fr*16 + cr + r) * 132 + wc + fc*16 + cc] = acc[fr][fc][r];
  __syncthreads();
  // phase C: 16 groups x 16 lanes; group gq owns rows gq*8..gq*8+7; lane ln owns 8 cols
  int gq = t >> 4, ln = t & 15;
  #pragma unroll
  for (int it = 0; it < 8; ++it) {
    int r = gq * 8 + it, row = row0 + r;
    if (row >= NV) continue;
    float c[8];
    #pragma unroll
    for (int e = 0; e < 8; e++) c[e] = accum[r * 132 + ln * 8 + e];
    int sv[27];                                    // all pslot loads issued together
    #pragma unroll
    for (int k = 0; k < 27; k++) sv[k] = (k == 13) ? -1 : pslot[k * NV + row];
    #pragma unroll
    for (int k = 0; k < 27; k++) {
      int s = sv[k];
      if (s >= 0) {
        bf16x8 pv = *(const bf16x8*)(partial + ((long)k*CAP + s) * 128 + ln * 8);
        #pragma unroll
        for (int e = 0; e < 8; e++) c[e] += bf2f((u16)pv[e]);
      }
    }
    int col = ln * 8;
    float o[8];
    #pragma unroll
    for (int e = 0; e < 8; e++) o[e] = fmaxf(c[e] * ss[col + e] + tt[col + e], 0.f);
    int4 q;
    q.x = (int)f2bf(o[0]) | ((int)f2bf(o[1]) << 16);
    q.y = (int)f2bf(o[2]) | ((int)f2bf(o[3]) << 16);
    q.z = (int)f2bf(o[4]) | ((int)f2bf(o[5]) << 16);
    q.w = (int)f2bf(o[6]) | ((int)f2bf(o[7]) << 16);
    *(int4*)(h1 + (long)row * 128 + col) = q;
  }
}

// ---------- conv2 reduce: NiN skip GEMM + self GEMM + partial gather-sum -> out ----------
__global__ __launch_bounds__(256, 2) void k_reduce2(const float* __restrict__ feat,
                                                    const u16* __restrict__ lwt,
                                                    const u16* __restrict__ h1,
                                                    const u16* __restrict__ w2t,
                                                    const int* __restrict__ pslot,
                                                    const u16* __restrict__ partial,
                                                    float* __restrict__ out) {
  __shared__ __align__(16) char smem[128 * 132 * 4];  // union: As [128][136] u16 | accum [128][132] f32
  __shared__ int sidx[128];
  u16*   As    = (u16*)smem;
  float* accum = (float*)smem;
  int t = threadIdx.x, row0 = blockIdx.x * 128;
  if (t < 128) sidx[t] = (row0 + t < NV) ? row0 + t : -1;
  __syncthreads();
  f32x4 acc[4][4] = {};
  stage_feat(feat, row0, As);                      // K=64 NiN pass (stride 72 region)
  __syncthreads();
  mma_tile<64>(As, lwt, acc);
  __syncthreads();
  stage_rows<128, 128>(h1, sidx, As);              // K=128 self pass (stride 136)
  __syncthreads();
  mma_tile<128>(As, w2t + 13 * 16384, acc);
  __syncthreads();                                 // As dead -> accum
  int lane = t & 63, wave = t >> 6;
  int wr = (wave >> 1) * 64, wc = (wave & 1) * 64, cr = (lane >> 4) * 4, cc = lane & 15;
  #pragma unroll
  for (int fr = 0; fr < 4; fr++)
    #pragma unroll
    for (int r = 0; r < 4; r++)
      #pragma unroll
      for (int fc = 0; fc < 4; fc++)
        accum[(wr + fr*16 + cr + r) * 132 + wc + fc*16 + cc] = acc[fr][fc][r];
  __syncthreads();
  int gq = t >> 4, ln = t & 15;
  #pragma unroll
  for (int it = 0; it < 8; ++it) {
    int r = gq * 8 + it, row = row0 + r;
    if (row >= NV) continue;
    float c[8];
    #pragma unroll
    for (int e = 0; e < 8; e++) c[e] = accum[r * 132 + ln * 8 + e];
    int sv[27];
    #pragma unroll
    for (int k = 0; k < 27; k++) sv[k] = (k == 13) ? -1 : pslot[k * NV + row];
    #pragma unroll
    for (int k = 0; k < 27; k++) {
      int s = sv[k];
      if (s >= 0) {
        bf16x8 pv = *(const bf16x8*)(partial + ((long)k*CAP + s) * 128 + ln * 8);
        #pragma unroll
        for (int e = 0; e < 8; e++) c[e] += bf2f((u16)pv[e]);
      }
    }
    f32x4 v0, v1;
    #pragma unroll
    for (int e = 0; e < 4; e++) { v0[e] = c[e]; v1[e] = c[4 + e]; }
    *(f32x4*)(out + (long)row * 128 + ln * 8)     = v0;
    *(f32x4*)(out + (long)row * 128 + ln * 8 + 4) = v1;
  }
}

extern "C" void kernel_launch(void* const* d_in, const int* in_sizes, int n_in,
                              void* d_out, int out_size, void* d_ws, size_t ws_size,
                              hipStream_t stream) {
  const float* feat = (const float*)d_in[0];
  const int*   pos  = (const int*)d_in[1];
  const float* linw = (const float*)d_in[2];
  const float* g1 = (const float*)d_in[3], *b1 = (const float*)d_in[4];
  const float* m1 = (const float*)d_in[5], *v1 = (const float*)d_in[6];
  const float* W1 = (const float*)d_in[7];
  const float* g2 = (const float*)d_in[8], *b2 = (const float*)d_in[9];
  const float* m2 = (const float*)d_in[10], *v2 = (const float*)d_in[11];
  const float* W2 = (const float*)d_in[12];

  if (ws_size < WS_NEED) return;  // insufficient scratch; fail visibly rather than corrupt

  char* ws = (char*)d_ws;
  u16*   partial = (u16*)(ws + OFF_PART);
  int*   grid    = (int*)(ws + OFF_GRID);          // overlays partial head, dead before it
  int*   pin     = (int*)(ws + OFF_PIN);
  int*   pslot   = (int*)(ws + OFF_PSL);
  int*   counts  = (int*)(ws + OFF_CNT);
  u16*   h0      = (u16*)(ws + OFF_H0);
  u16*   h1      = (u16*)(ws + OFF_H1);
  u16*   w1t     = (u16*)(ws + OFF_W1T);
  u16*   w2t     = (u16*)(ws + OFF_W2T);
  u16*   lwt     = (u16*)(ws + OFF_LINW);
  float* out     = (float*)d_out;

  hipMemsetAsync(grid,  0xFF, (size_t)G3 * 4, stream);       // grid  = -1
  hipMemsetAsync(pslot, 0xFF, (size_t)27 * NV * 4, stream);  // pslot = -1
  hipMemsetAsync(counts, 0, 27 * CPAD * 4, stream);

  k_grid  <<<(NV + 255) / 256, 256, 0, stream>>>(pos, grid);
  k_pairs <<<(NV + 255) / 256, 256, 0, stream>>>(pos, grid, pin, pslot, counts);
  k_bn1   <<<(NV * 16) / 256, 256, 0, stream>>>(feat, g1, b1, m1, v1, h0);
  k_weights<<<55, 256, 0, stream>>>(W1, W2, linw, w1t, w2t, lwt);

  dim3 gt((NV + 127) / 128);
  dim3 gscat(CAP / 128, 27);
  k_scat<64, 64>   <<<gscat, 256, 0, stream>>>(h0, w1t, pin, counts, partial);
  k_reduce1        <<<gt, 256, 0, stream>>>(h0, w1t, pslot, partial, g2, b2, m2, v2, h1);
  k_scat<128, 128> <<<gscat, 256, 0, stream>>>(h1, w2t, pin, counts, partial);
  k_reduce2        <<<gt, 256, 0, stream>>>(feat, lwt, h1, w2t, pslot, partial, out);
}

// Round 3
// 795.685 us; speedup vs baseline: 1.6589x; 1.1311x over previous
//
#include <hip/hip_runtime.h>

#define G    160
#define G3   (G*G*G)          // 4,096,000
#define NV   300000
#define EPS  1e-4f
#define CAP  24576            // per-tap pair capacity (expected ~22.0k, +18 sigma)
#define CPAD 32               // counts[k] lives at counts[k*CPAD]: one 128B line per counter

typedef unsigned short u16;
typedef __attribute__((ext_vector_type(8))) short bf16x8;
typedef __attribute__((ext_vector_type(4))) float f32x4;

// ---- workspace layout (bytes) ----
// R5: R4 structure (pair-list gather-GEMM + bf16 partials + fused reduce) with
// latency fixes: bf16 accum spill (LDS 68K->35K, 2->4 blocks/CU) and row-major
// pslot [NV][28] (per-row tap list = 2 cache lines instead of 27).
#define OFF_PART 0ull                          // 27*CAP*128*2 = 169,869,312
#define OFF_GRID 0ull                          // 16,384,000 (dies before partial writes)
#define OFF_PIN  169869312ull                  // 27*CAP*4 = 2,654,208
#define OFF_PSL  (OFF_PIN + 2654208ull)        // NV*28*4  = 33,600,000
#define OFF_CNT  (OFF_PSL + 33600000ull)       // 4096
#define OFF_H0   (OFF_CNT + 4096ull)           // NV*64*2  = 38,400,000
#define OFF_H1   (OFF_H0  + 38400000ull)       // NV*128*2 = 76,800,000
#define OFF_W1T  (OFF_H1  + 76800000ull)       // 27*128*64*2  (B^T layout [k][cout][cin])
#define OFF_W2T  (OFF_W1T + 442368ull)         // 27*128*128*2
#define OFF_LINW (OFF_W2T + 884736ull)         // 128*64*2
#define WS_NEED  (OFF_LINW + 16384ull)         // ~322.7 MB

__device__ __forceinline__ u16 f2bf(float f) {   // fp32 -> bf16 RNE
  unsigned u = __float_as_uint(f);
  return (u16)((u + 0x7fffu + ((u >> 16) & 1u)) >> 16);
}
__device__ __forceinline__ float bf2f(u16 h) {
  return __uint_as_float(((unsigned)h) << 16);
}

// ---------- phase 1: hash grid + per-tap pair lists + inverse slot map ----------
__global__ void k_grid(const int* __restrict__ pos, int* __restrict__ grid) {
  int i = blockIdx.x * 256 + threadIdx.x;
  if (i < NV)
    grid[(pos[3*i] * G + pos[3*i+1]) * G + pos[3*i+2]] = i;
}

// LDS-hierarchical slot allocation (R2-proven: 1 global atomic per block per tap,
// counters padded to separate L2 lines). pslot row-major: pslot[i*28+k] = slot.
__global__ __launch_bounds__(256) void k_pairs(const int* __restrict__ pos,
                        const int* __restrict__ grid,
                        int* __restrict__ pin, int* __restrict__ pslot,
                        int* __restrict__ counts) {
  __shared__ int lcnt[27];
  __shared__ int wboff[27][4];
  __shared__ int gbase[27];
  int t = threadIdx.x, lane = t & 63, wv = t >> 6;
  if (t < 27) lcnt[t] = 0;
  int i = blockIdx.x * 256 + t;
  bool act = (i < NV);
  int p0 = 0, p1 = 1 << 20, p2 = 0;              // inactive threads -> always OOB
  if (act) { p0 = pos[3*i]; p1 = pos[3*i+1]; p2 = pos[3*i+2]; }
  __syncthreads();                               // lcnt zeroed

  int j[26];
  #pragma unroll
  for (int kk = 0; kk < 26; kk++) {              // all 26 loads independent & in flight
    int k = kk < 13 ? kk : kk + 1;
    int q0 = p0 + k/9 - 1, q1 = p1 + (k/3)%3 - 1, q2 = p2 + k%3 - 1;
    bool inb = (q0 >= 0 && q0 < G && q1 >= 0 && q1 < G && q2 >= 0 && q2 < G);
    int addr = inb ? (q0*G + q1)*G + q2 : 0;     // clamped: unconditional load
    int jj = grid[addr];
    j[kk] = inb ? jj : -1;
  }

  unsigned long long m[26];                      // wave-uniform -> SGPRs
  #pragma unroll
  for (int kk = 0; kk < 26; kk++) m[kk] = __ballot(j[kk] >= 0);

  #pragma unroll
  for (int kk = 0; kk < 26; kk++) {              // per-block aggregation in LDS
    int k = kk < 13 ? kk : kk + 1;
    if (lane == 0) wboff[k][wv] = atomicAdd(&lcnt[k], (int)__popcll(m[kk]));
  }
  __syncthreads();
  if (t < 27 && t != 13)                         // 27 concurrent atomics, separate L2 lines
    gbase[t] = atomicAdd(&counts[t * CPAD], lcnt[t]);
  __syncthreads();

  #pragma unroll
  for (int kk = 0; kk < 26; kk++) {
    if (j[kk] >= 0) {
      int k = kk < 13 ? kk : kk + 1;
      int slot = gbase[k] + wboff[k][wv] + (int)__popcll(m[kk] & ((1ull << lane) - 1ull));
      if (slot < CAP) {
        pin[k*CAP + slot] = j[kk];
        pslot[i*28 + k] = slot;
      }
    }
  }
}

// ---------- phase 2: BN1+ReLU -> bf16 h0 ; weight cast/transpose ----------
__global__ void k_bn1(const float* __restrict__ feat, const float* g, const float* b,
                      const float* m, const float* v, u16* __restrict__ h0) {
  __shared__ float ss[64], tt[64];
  int t = threadIdx.x;
  if (t < 64) { float s = g[t] * rsqrtf(v[t] + EPS); ss[t] = s; tt[t] = b[t] - m[t]*s; }
  __syncthreads();
  long gt = (long)blockIdx.x * 256 + t;            // one thread per 4 elems
  if (gt >= (long)NV * 16) return;
  int c = (int)(gt & 15) * 4;
  float4 x = ((const float4*)feat)[gt];
  ushort4 q;
  q.x = f2bf(fmaxf(x.x*ss[c  ] + tt[c  ], 0.f));
  q.y = f2bf(fmaxf(x.y*ss[c+1] + tt[c+1], 0.f));
  q.z = f2bf(fmaxf(x.z*ss[c+2] + tt[c+2], 0.f));
  q.w = f2bf(fmaxf(x.w*ss[c+3] + tt[c+3], 0.f));
  ((ushort4*)h0)[gt] = q;
}

// W -> bf16, transposed to [k][cout][cin] so MFMA B-frags are k-contiguous.
__global__ void k_weights(const float* __restrict__ W1, const float* __restrict__ W2,
                          const float* __restrict__ linw,
                          u16* __restrict__ w1t, u16* __restrict__ w2t, u16* __restrict__ lwt) {
  __shared__ float tmp[8192];
  int b = blockIdx.x, t = threadIdx.x;
  if (b < 27) {                                    // W1[k]: [64][128] -> [128][64]
    const float* src = W1 + b * 8192;
    u16* dst = w1t + b * 8192;
    for (int u = t; u < 8192; u += 256) tmp[u] = src[u];
    __syncthreads();
    for (int u = t; u < 8192; u += 256) { int c = u >> 6, a = u & 63; dst[c*64 + a] = f2bf(tmp[a*128 + c]); }
  } else if (b < 54) {                             // W2[k]: [128][128] -> [128][128]^T, two halves
    int k = b - 27;
    const float* src = W2 + k * 16384;
    u16* dst = w2t + k * 16384;
    for (int h = 0; h < 2; h++) {
      for (int u = t; u < 8192; u += 256) tmp[u] = src[h*8192 + u];
      __syncthreads();
      for (int u = t; u < 8192; u += 256) { int c = u >> 6, a = u & 63; dst[c*128 + h*64 + a] = f2bf(tmp[a*128 + c]); }
      __syncthreads();
    }
  } else {                                         // lin_w [128][64] is already B^T layout
    for (int u = t; u < 8192; u += 256) lwt[u] = f2bf(linw[u]);
  }
}

// ---------- GEMM building blocks (128x128 tile, 4 waves, 64x64 quadrants) ----------
template<int K, int RS>   // K: reduce dim; RS: global row stride (bf16 elems)
__device__ __forceinline__ void stage_rows(const u16* __restrict__ src, const int* sidx, u16* lds) {
  const int LPR = K / 8, RPI = 256 / LPR;          // 16B loaders per row, rows per iter
  int t = threadIdx.x, o = t % LPR, r0 = t / LPR;
  #pragma unroll
  for (int r = r0; r < 128; r += RPI) {
    int j = sidx[r];
    int4 val = make_int4(0, 0, 0, 0);
    if (j >= 0) val = *(const int4*)(src + (long)j * RS + o * 8);
    *(int4*)(lds + r * (K + 8) + o * 8) = val;     // +8 elem pad: low-order LDS banking
  }
}

__device__ __forceinline__ void stage_feat(const float* __restrict__ feat, int row0, u16* lds) {
  int t = threadIdx.x, o = t & 15, r0 = t >> 4;    // fp32->bf16 on the fly, K=64
  #pragma unroll
  for (int r = r0; r < 128; r += 16) {
    int row = row0 + r;
    float4 x = make_float4(0.f, 0.f, 0.f, 0.f);
    if (row < NV) x = *(const float4*)(feat + (long)row * 64 + o * 4);
    ushort4 q; q.x = f2bf(x.x); q.y = f2bf(x.y); q.z = f2bf(x.z); q.w = f2bf(x.w);
    *(ushort4*)(lds + r * 72 + o * 4) = q;
  }
}

template<int K>           // A from padded LDS; B-frags straight from L2-hot transposed weights
__device__ __forceinline__ void mma_tile(const u16* As, const u16* __restrict__ wt, f32x4 acc[4][4]) {
  int lane = threadIdx.x & 63, wave = threadIdx.x >> 6;
  int wr = (wave >> 1) * 64, wc = (wave & 1) * 64;
  int lr = lane & 15, lk = (lane >> 4) * 8;
  #pragma unroll
  for (int kk = 0; kk < K; kk += 32) {
    bf16x8 a[4], b[4];
    #pragma unroll
    for (int f = 0; f < 4; f++) a[f] = *(const bf16x8*)(As + (wr + f*16 + lr) * (K + 8) + kk + lk);
    #pragma unroll
    for (int f = 0; f < 4; f++) b[f] = *(const bf16x8*)(wt + (wc + f*16 + lr) * K + kk + lk);
    #pragma unroll
    for (int fr = 0; fr < 4; fr++)
      #pragma unroll
      for (int fc = 0; fc < 4; fc++)
        acc[fr][fc] = __builtin_amdgcn_mfma_f32_16x16x32_bf16(a[fr], b[fc], acc[fr][fc], 0, 0, 0);
  }
}

// Spill f32 acc -> bf16 LDS tile [128][136] (reuses the staging buffer).
__device__ __forceinline__ void spill_acc(const f32x4 acc[4][4], u16* As) {
  int t = threadIdx.x, lane = t & 63, wave = t >> 6;
  int wr = (wave >> 1) * 64, wc = (wave & 1) * 64, cr = (lane >> 4) * 4, cc = lane & 15;
  #pragma unroll
  for (int fr = 0; fr < 4; fr++)
    #pragma unroll
    for (int r = 0; r < 4; r++)
      #pragma unroll
      for (int fc = 0; fc < 4; fc++)
        As[(wr + fr*16 + cr + r) * 136 + wc + fc*16 + cc] = f2bf(acc[fr][fc][r]);
}

// Phase C: c[8] = accum(bf16 LDS) + sum of valid bf16 partial rows.
// Per-row tap list is 7 contiguous int4 (pslot row-major, stride 28).
__device__ __forceinline__ void gather_sum(const u16* As, int r, int ln, int row,
                                           const int* __restrict__ pslot,
                                           const u16* __restrict__ partial, float c[8]) {
  int4 sv4[7];
  #pragma unroll
  for (int q = 0; q < 7; q++) sv4[q] = *(const int4*)(pslot + (long)row * 28 + q * 4);
  bf16x8 av = *(const bf16x8*)(As + r * 136 + ln * 8);
  #pragma unroll
  for (int e = 0; e < 8; e++) c[e] = bf2f((u16)av[e]);
  const int* sv = (const int*)sv4;
  #pragma unroll
  for (int k = 0; k < 27; k++) {                   // k compile-time: static sv4 indexing
    int s = sv[k];
    if (s >= 0) {
      bf16x8 pv = *(const bf16x8*)(partial + ((long)k * CAP + s) * 128 + ln * 8);
      #pragma unroll
      for (int e = 0; e < 8; e++) c[e] += bf2f((u16)pv[e]);
    }
  }
}

// ---------- non-self taps: gather-GEMM -> bf16 partial rows (plain stores, no atomics) ----------
template<int K, int RS>
__global__ __launch_bounds__(256, 4) void k_scat(const u16* __restrict__ h, const u16* __restrict__ wt,
                                                 const int* __restrict__ pin,
                                                 const int* __restrict__ counts,
                                                 u16* __restrict__ partial) {
  int k = blockIdx.y;
  int cnt = counts[k * CPAD]; if (cnt > CAP) cnt = CAP;
  int base = blockIdx.x * 128;
  if (base >= cnt) return;                         // k==13 (cnt 0) and tail tiles exit here
  __shared__ __align__(16) u16 As[128 * 136];      // stage: [128][K+8]; epilogue: [128][136]
  __shared__ int sin[128];
  int t = threadIdx.x;
  if (t < 128) sin[t] = (base + t < cnt) ? pin[k*CAP + base + t] : -1;
  __syncthreads();
  stage_rows<K, RS>(h, sin, As);
  __syncthreads();
  f32x4 acc[4][4] = {};
  mma_tile<K>(As, wt + k * (K * 128), acc);
  __syncthreads();                                 // As free; reuse as bf16 [128][136]
  spill_acc(acc, As);
  __syncthreads();
  #pragma unroll
  for (int u = t; u < 2048; u += 256) {            // coalesced 256B-row copy-out
    int r = u >> 4, o = u & 15;
    if (base + r < cnt)
      *(int4*)(partial + ((long)k*CAP + base + r) * 128 + o * 8) = *(const int4*)(As + r * 136 + o * 8);
  }
}

// ---------- conv1 reduce: self GEMM + partial gather-sum + BN2+ReLU -> bf16 h1 ----------
__global__ __launch_bounds__(256, 4) void k_reduce1(const u16* __restrict__ h0,
                                                    const u16* __restrict__ w1t,
                                                    const int* __restrict__ pslot,
                                                    const u16* __restrict__ partial,
                                                    const float* g, const float* b,
                                                    const float* m, const float* v,
                                                    u16* __restrict__ h1) {
  __shared__ __align__(16) u16 As[128 * 136];      // stage [128][72] -> bf16 accum [128][136]
  __shared__ float ss[128], tt[128];
  __shared__ int sidx[128];
  int t = threadIdx.x, row0 = blockIdx.x * 128;
  if (t < 128) {
    float s = g[t] * rsqrtf(v[t] + EPS); ss[t] = s; tt[t] = b[t] - m[t]*s;
    sidx[t] = (row0 + t < NV) ? row0 + t : -1;
  }
  __syncthreads();
  stage_rows<64, 64>(h0, sidx, As);
  __syncthreads();
  f32x4 acc[4][4] = {};
  mma_tile<64>(As, w1t + 13 * 8192, acc);
  __syncthreads();                                 // stage data dead -> bf16 accum
  spill_acc(acc, As);
  __syncthreads();
  int gq = t >> 4, ln = t & 15;
  #pragma unroll 2
  for (int it = 0; it < 8; ++it) {
    int r = gq * 8 + it, row = row0 + r;
    if (row >= NV) continue;
    float c[8];
    gather_sum(As, r, ln, row, pslot, partial, c);
    int col = ln * 8;
    float o[8];
    #pragma unroll
    for (int e = 0; e < 8; e++) o[e] = fmaxf(c[e] * ss[col + e] + tt[col + e], 0.f);
    int4 q;
    q.x = (int)f2bf(o[0]) | ((int)f2bf(o[1]) << 16);
    q.y = (int)f2bf(o[2]) | ((int)f2bf(o[3]) << 16);
    q.z = (int)f2bf(o[4]) | ((int)f2bf(o[5]) << 16);
    q.w = (int)f2bf(o[6]) | ((int)f2bf(o[7]) << 16);
    *(int4*)(h1 + (long)row * 128 + col) = q;
  }
}

// ---------- conv2 reduce: NiN skip GEMM + self GEMM + partial gather-sum -> out ----------
__global__ __launch_bounds__(256, 4) void k_reduce2(const float* __restrict__ feat,
                                                    const u16* __restrict__ lwt,
                                                    const u16* __restrict__ h1,
                                                    const u16* __restrict__ w2t,
                                                    const int* __restrict__ pslot,
                                                    const u16* __restrict__ partial,
                                                    float* __restrict__ out) {
  __shared__ __align__(16) u16 As[128 * 136];      // stage [128][72]/[128][136] -> bf16 accum
  __shared__ int sidx[128];
  int t = threadIdx.x, row0 = blockIdx.x * 128;
  if (t < 128) sidx[t] = (row0 + t < NV) ? row0 + t : -1;
  __syncthreads();
  f32x4 acc[4][4] = {};
  stage_feat(feat, row0, As);                      // K=64 NiN pass (stride 72 region)
  __syncthreads();
  mma_tile<64>(As, lwt, acc);
  __syncthreads();
  stage_rows<128, 128>(h1, sidx, As);              // K=128 self pass (stride 136)
  __syncthreads();
  mma_tile<128>(As, w2t + 13 * 16384, acc);
  __syncthreads();                                 // stage data dead -> bf16 accum
  spill_acc(acc, As);
  __syncthreads();
  int gq = t >> 4, ln = t & 15;
  #pragma unroll 2
  for (int it = 0; it < 8; ++it) {
    int r = gq * 8 + it, row = row0 + r;
    if (row >= NV) continue;
    float c[8];
    gather_sum(As, r, ln, row, pslot, partial, c);
    f32x4 v0, v1;
    #pragma unroll
    for (int e = 0; e < 4; e++) { v0[e] = c[e]; v1[e] = c[4 + e]; }
    *(f32x4*)(out + (long)row * 128 + ln * 8)     = v0;
    *(f32x4*)(out + (long)row * 128 + ln * 8 + 4) = v1;
  }
}

extern "C" void kernel_launch(void* const* d_in, const int* in_sizes, int n_in,
                              void* d_out, int out_size, void* d_ws, size_t ws_size,
                              hipStream_t stream) {
  const float* feat = (const float*)d_in[0];
  const int*   pos  = (const int*)d_in[1];
  const float* linw = (const float*)d_in[2];
  const float* g1 = (const float*)d_in[3], *b1 = (const float*)d_in[4];
  const float* m1 = (const float*)d_in[5], *v1 = (const float*)d_in[6];
  const float* W1 = (const float*)d_in[7];
  const float* g2 = (const float*)d_in[8], *b2 = (const float*)d_in[9];
  const float* m2 = (const float*)d_in[10], *v2 = (const float*)d_in[11];
  const float* W2 = (const float*)d_in[12];

  if (ws_size < WS_NEED) return;  // insufficient scratch; fail visibly rather than corrupt

  char* ws = (char*)d_ws;
  u16*   partial = (u16*)(ws + OFF_PART);
  int*   grid    = (int*)(ws + OFF_GRID);          // overlays partial head, dead before it
  int*   pin     = (int*)(ws + OFF_PIN);
  int*   pslot   = (int*)(ws + OFF_PSL);
  int*   counts  = (int*)(ws + OFF_CNT);
  u16*   h0      = (u16*)(ws + OFF_H0);
  u16*   h1      = (u16*)(ws + OFF_H1);
  u16*   w1t     = (u16*)(ws + OFF_W1T);
  u16*   w2t     = (u16*)(ws + OFF_W2T);
  u16*   lwt     = (u16*)(ws + OFF_LINW);
  float* out     = (float*)d_out;

  hipMemsetAsync(grid,  0xFF, (size_t)G3 * 4, stream);       // grid  = -1
  hipMemsetAsync(pslot, 0xFF, (size_t)NV * 28 * 4, stream);  // pslot = -1
  hipMemsetAsync(counts, 0, 27 * CPAD * 4, stream);

  k_grid  <<<(NV + 255) / 256, 256, 0, stream>>>(pos, grid);
  k_pairs <<<(NV + 255) / 256, 256, 0, stream>>>(pos, grid, pin, pslot, counts);
  k_bn1   <<<(NV * 16) / 256, 256, 0, stream>>>(feat, g1, b1, m1, v1, h0);
  k_weights<<<55, 256, 0, stream>>>(W1, W2, linw, w1t, w2t, lwt);

  dim3 gt((NV + 127) / 128);
  dim3 gscat(CAP / 128, 27);
  k_scat<64, 64>   <<<gscat, 256, 0, stream>>>(h0, w1t, pin, counts, partial);
  k_reduce1        <<<gt, 256, 0, stream>>>(h0, w1t, pslot, partial, g2, b2, m2, v2, h1);
  k_scat<128, 128> <<<gscat, 256, 0, stream>>>(h1, w2t, pin, counts, partial);
  k_reduce2        <<<gt, 256, 0, stream>>>(feat, lwt, h1, w2t, pslot, partial, out);
}

// Round 4
// 782.437 us; speedup vs baseline: 1.6869x; 1.0169x over previous
//
#include <hip/hip_runtime.h>

#define G    160
#define G3   (G*G*G)          // 4,096,000
#define NV   300000
#define EPS  1e-4f
#define CAP  24576            // per-tap pair capacity (expected ~22.0k, +18 sigma)
#define CPAD 32               // counts[k] lives at counts[k*CPAD]: one 128B line per counter

typedef unsigned short u16;
typedef __attribute__((ext_vector_type(8))) short bf16x8;
typedef __attribute__((ext_vector_type(4))) float f32x4;

// ---- workspace layout (bytes) ----
// R6: reduce kernels split into dense self-GEMM (k_self*) + pure high-occupancy
// gather (k_gather*). Self results ride in h1 in place (bf16), zero extra ws.
// pslot packed to u16 [NV][32]: one 64B cache line per output row.
#define OFF_PART 0ull                          // 27*CAP*128*2 = 169,869,312
#define OFF_GRID 0ull                          // 16,384,000 (dies before partial writes)
#define OFF_PIN  169869312ull                  // 27*CAP*4 = 2,654,208
#define OFF_PSL  (OFF_PIN + 2654208ull)        // NV*32*2  = 19,200,000 (u16 slots)
#define OFF_CNT  (OFF_PSL + 19200000ull)       // 4096
#define OFF_H0   (OFF_CNT + 4096ull)           // NV*64*2  = 38,400,000
#define OFF_H1   (OFF_H0  + 38400000ull)       // NV*128*2 = 76,800,000
#define OFF_W1T  (OFF_H1  + 76800000ull)       // 27*128*64*2  (B^T layout [k][cout][cin])
#define OFF_W2T  (OFF_W1T + 442368ull)         // 27*128*128*2
#define OFF_LINW (OFF_W2T + 884736ull)         // 128*64*2
#define OFF_BNP  (OFF_LINW + 16384ull)         // 2*128*4 (BN2 scale|shift)
#define WS_NEED  (OFF_BNP + 1024ull)           // ~308.3 MB (< R5's 322.7, proven ok)

__device__ __forceinline__ u16 f2bf(float f) {   // fp32 -> bf16 RNE
  unsigned u = __float_as_uint(f);
  return (u16)((u + 0x7fffu + ((u >> 16) & 1u)) >> 16);
}
__device__ __forceinline__ float bf2f(u16 h) {
  return __uint_as_float(((unsigned)h) << 16);
}

// ---------- phase 1: hash grid + per-tap pair lists + inverse slot map ----------
__global__ void k_grid(const int* __restrict__ pos, int* __restrict__ grid) {
  int i = blockIdx.x * 256 + threadIdx.x;
  if (i < NV)
    grid[(pos[3*i] * G + pos[3*i+1]) * G + pos[3*i+2]] = i;
}

// LDS-hierarchical slot allocation (R2-proven). pslot u16 row-major:
// pslot[i*32 + k] = slot (0xFFFF = none); whole tap list of a row = 64B line.
__global__ __launch_bounds__(256) void k_pairs(const int* __restrict__ pos,
                        const int* __restrict__ grid,
                        int* __restrict__ pin, u16* __restrict__ pslot,
                        int* __restrict__ counts) {
  __shared__ int lcnt[27];
  __shared__ int wboff[27][4];
  __shared__ int gbase[27];
  int t = threadIdx.x, lane = t & 63, wv = t >> 6;
  if (t < 27) lcnt[t] = 0;
  int i = blockIdx.x * 256 + t;
  bool act = (i < NV);
  int p0 = 0, p1 = 1 << 20, p2 = 0;              // inactive threads -> always OOB
  if (act) { p0 = pos[3*i]; p1 = pos[3*i+1]; p2 = pos[3*i+2]; }
  __syncthreads();                               // lcnt zeroed

  int j[26];
  #pragma unroll
  for (int kk = 0; kk < 26; kk++) {              // all 26 loads independent & in flight
    int k = kk < 13 ? kk : kk + 1;
    int q0 = p0 + k/9 - 1, q1 = p1 + (k/3)%3 - 1, q2 = p2 + k%3 - 1;
    bool inb = (q0 >= 0 && q0 < G && q1 >= 0 && q1 < G && q2 >= 0 && q2 < G);
    int addr = inb ? (q0*G + q1)*G + q2 : 0;     // clamped: unconditional load
    int jj = grid[addr];
    j[kk] = inb ? jj : -1;
  }

  unsigned long long m[26];                      // wave-uniform -> SGPRs
  #pragma unroll
  for (int kk = 0; kk < 26; kk++) m[kk] = __ballot(j[kk] >= 0);

  #pragma unroll
  for (int kk = 0; kk < 26; kk++) {              // per-block aggregation in LDS
    int k = kk < 13 ? kk : kk + 1;
    if (lane == 0) wboff[k][wv] = atomicAdd(&lcnt[k], (int)__popcll(m[kk]));
  }
  __syncthreads();
  if (t < 27 && t != 13)                         // 27 concurrent atomics, separate L2 lines
    gbase[t] = atomicAdd(&counts[t * CPAD], lcnt[t]);
  __syncthreads();

  #pragma unroll
  for (int kk = 0; kk < 26; kk++) {
    if (j[kk] >= 0) {
      int k = kk < 13 ? kk : kk + 1;
      int slot = gbase[k] + wboff[k][wv] + (int)__popcll(m[kk] & ((1ull << lane) - 1ull));
      if (slot < CAP) {
        pin[k*CAP + slot] = j[kk];
        pslot[(long)i*32 + k] = (u16)slot;
      }
    }
  }
}

// ---------- phase 2: BN1+ReLU -> bf16 h0 ; weight cast/transpose + BN2 precompute ----------
__global__ void k_bn1(const float* __restrict__ feat, const float* g, const float* b,
                      const float* m, const float* v, u16* __restrict__ h0) {
  __shared__ float ss[64], tt[64];
  int t = threadIdx.x;
  if (t < 64) { float s = g[t] * rsqrtf(v[t] + EPS); ss[t] = s; tt[t] = b[t] - m[t]*s; }
  __syncthreads();
  long gt = (long)blockIdx.x * 256 + t;            // one thread per 4 elems
  if (gt >= (long)NV * 16) return;
  int c = (int)(gt & 15) * 4;
  float4 x = ((const float4*)feat)[gt];
  ushort4 q;
  q.x = f2bf(fmaxf(x.x*ss[c  ] + tt[c  ], 0.f));
  q.y = f2bf(fmaxf(x.y*ss[c+1] + tt[c+1], 0.f));
  q.z = f2bf(fmaxf(x.z*ss[c+2] + tt[c+2], 0.f));
  q.w = f2bf(fmaxf(x.w*ss[c+3] + tt[c+3], 0.f));
  ((ushort4*)h0)[gt] = q;
}

// W -> bf16, transposed to [k][cout][cin]; block 55 precomputes BN2 scale/shift.
__global__ void k_weights(const float* __restrict__ W1, const float* __restrict__ W2,
                          const float* __restrict__ linw,
                          const float* __restrict__ g2, const float* __restrict__ b2,
                          const float* __restrict__ m2, const float* __restrict__ v2,
                          u16* __restrict__ w1t, u16* __restrict__ w2t, u16* __restrict__ lwt,
                          float* __restrict__ bnp) {
  __shared__ float tmp[8192];
  int b = blockIdx.x, t = threadIdx.x;
  if (b < 27) {                                    // W1[k]: [64][128] -> [128][64]
    const float* src = W1 + b * 8192;
    u16* dst = w1t + b * 8192;
    for (int u = t; u < 8192; u += 256) tmp[u] = src[u];
    __syncthreads();
    for (int u = t; u < 8192; u += 256) { int c = u >> 6, a = u & 63; dst[c*64 + a] = f2bf(tmp[a*128 + c]); }
  } else if (b < 54) {                             // W2[k]: [128][128] -> [128][128]^T, two halves
    int k = b - 27;
    const float* src = W2 + k * 16384;
    u16* dst = w2t + k * 16384;
    for (int h = 0; h < 2; h++) {
      for (int u = t; u < 8192; u += 256) tmp[u] = src[h*8192 + u];
      __syncthreads();
      for (int u = t; u < 8192; u += 256) { int c = u >> 6, a = u & 63; dst[c*128 + h*64 + a] = f2bf(tmp[a*128 + c]); }
      __syncthreads();
    }
  } else if (b == 54) {                            // lin_w [128][64] is already B^T layout
    for (int u = t; u < 8192; u += 256) lwt[u] = f2bf(linw[u]);
  } else {                                         // BN2 scale|shift
    if (t < 128) { float s = g2[t] * rsqrtf(v2[t] + EPS); bnp[t] = s; bnp[128 + t] = b2[t] - m2[t]*s; }
  }
}

// ---------- GEMM building blocks (128x128 tile, 4 waves, 64x64 quadrants) ----------
template<int K, int RS>   // K: reduce dim; RS: global row stride (bf16 elems)
__device__ __forceinline__ void stage_rows(const u16* __restrict__ src, const int* sidx, u16* lds) {
  const int LPR = K / 8, RPI = 256 / LPR;          // 16B loaders per row, rows per iter
  int t = threadIdx.x, o = t % LPR, r0 = t / LPR;
  #pragma unroll
  for (int r = r0; r < 128; r += RPI) {
    int j = sidx[r];
    int4 val = make_int4(0, 0, 0, 0);
    if (j >= 0) val = *(const int4*)(src + (long)j * RS + o * 8);
    *(int4*)(lds + r * (K + 8) + o * 8) = val;     // +8 elem pad: low-order LDS banking
  }
}

__device__ __forceinline__ void stage_feat(const float* __restrict__ feat, int row0, u16* lds) {
  int t = threadIdx.x, o = t & 15, r0 = t >> 4;    // fp32->bf16 on the fly, K=64
  #pragma unroll
  for (int r = r0; r < 128; r += 16) {
    int row = row0 + r;
    float4 x = make_float4(0.f, 0.f, 0.f, 0.f);
    if (row < NV) x = *(const float4*)(feat + (long)row * 64 + o * 4);
    ushort4 q; q.x = f2bf(x.x); q.y = f2bf(x.y); q.z = f2bf(x.z); q.w = f2bf(x.w);
    *(ushort4*)(lds + r * 72 + o * 4) = q;
  }
}

template<int K>           // A from padded LDS; B-frags straight from L2-hot transposed weights
__device__ __forceinline__ void mma_tile(const u16* As, const u16* __restrict__ wt, f32x4 acc[4][4]) {
  int lane = threadIdx.x & 63, wave = threadIdx.x >> 6;
  int wr = (wave >> 1) * 64, wc = (wave & 1) * 64;
  int lr = lane & 15, lk = (lane >> 4) * 8;
  #pragma unroll
  for (int kk = 0; kk < K; kk += 32) {
    bf16x8 a[4], b[4];
    #pragma unroll
    for (int f = 0; f < 4; f++) a[f] = *(const bf16x8*)(As + (wr + f*16 + lr) * (K + 8) + kk + lk);
    #pragma unroll
    for (int f = 0; f < 4; f++) b[f] = *(const bf16x8*)(wt + (wc + f*16 + lr) * K + kk + lk);
    #pragma unroll
    for (int fr = 0; fr < 4; fr++)
      #pragma unroll
      for (int fc = 0; fc < 4; fc++)
        acc[fr][fc] = __builtin_amdgcn_mfma_f32_16x16x32_bf16(a[fr], b[fc], acc[fr][fc], 0, 0, 0);
  }
}

// Spill f32 acc -> bf16 LDS tile [128][136] (reuses the staging buffer).
__device__ __forceinline__ void spill_acc(const f32x4 acc[4][4], u16* As) {
  int t = threadIdx.x, lane = t & 63, wave = t >> 6;
  int wr = (wave >> 1) * 64, wc = (wave & 1) * 64, cr = (lane >> 4) * 4, cc = lane & 15;
  #pragma unroll
  for (int fr = 0; fr < 4; fr++)
    #pragma unroll
    for (int r = 0; r < 4; r++)
      #pragma unroll
      for (int fc = 0; fc < 4; fc++)
        As[(wr + fr*16 + cr + r) * 136 + wc + fc*16 + cc] = f2bf(acc[fr][fc][r]);
}

// ---------- non-self taps: gather-GEMM -> bf16 partial rows (plain stores, no atomics) ----------
template<int K, int RS>
__global__ __launch_bounds__(256, 4) void k_scat(const u16* __restrict__ h, const u16* __restrict__ wt,
                                                 const int* __restrict__ pin,
                                                 const int* __restrict__ counts,
                                                 u16* __restrict__ partial) {
  int k = blockIdx.y;
  int cnt = counts[k * CPAD]; if (cnt > CAP) cnt = CAP;
  int base = blockIdx.x * 128;
  if (base >= cnt) return;                         // k==13 (cnt 0) and tail tiles exit here
  __shared__ __align__(16) u16 As[128 * 136];      // stage: [128][K+8]; epilogue: [128][136]
  __shared__ int sin[128];
  int t = threadIdx.x;
  if (t < 128) sin[t] = (base + t < cnt) ? pin[k*CAP + base + t] : -1;
  __syncthreads();
  stage_rows<K, RS>(h, sin, As);
  __syncthreads();
  f32x4 acc[4][4] = {};
  mma_tile<K>(As, wt + k * (K * 128), acc);
  __syncthreads();                                 // As free; reuse as bf16 [128][136]
  spill_acc(acc, As);
  __syncthreads();
  #pragma unroll
  for (int u = t; u < 2048; u += 256) {            // coalesced 256B-row copy-out
    int r = u >> 4, o = u & 15;
    if (base + r < cnt)
      *(int4*)(partial + ((long)k*CAP + base + r) * 128 + o * 8) = *(const int4*)(As + r * 136 + o * 8);
  }
}

// ---------- dense self-tap GEMMs: write bf16 rows into h1 ----------
__global__ __launch_bounds__(256, 4) void k_self1(const u16* __restrict__ h0,
                                                  const u16* __restrict__ w1t,
                                                  u16* __restrict__ h1) {
  __shared__ __align__(16) u16 As[128 * 136];
  __shared__ int sidx[128];
  int t = threadIdx.x, row0 = blockIdx.x * 128;
  if (t < 128) sidx[t] = (row0 + t < NV) ? row0 + t : -1;
  __syncthreads();
  stage_rows<64, 64>(h0, sidx, As);
  __syncthreads();
  f32x4 acc[4][4] = {};
  mma_tile<64>(As, w1t + 13 * 8192, acc);
  __syncthreads();
  spill_acc(acc, As);
  __syncthreads();
  #pragma unroll
  for (int u = t; u < 2048; u += 256) {
    int r = u >> 4, o = u & 15;
    if (row0 + r < NV)
      *(int4*)(h1 + (long)(row0 + r) * 128 + o * 8) = *(const int4*)(As + r * 136 + o * 8);
  }
}

// NiN skip + self tap for conv2; writes bf16 IN PLACE over h1 (own tile staged first).
__global__ __launch_bounds__(256, 4) void k_self2(const float* __restrict__ feat,
                                                  const u16* __restrict__ lwt,
                                                  u16* __restrict__ h1,
                                                  const u16* __restrict__ w2t) {
  __shared__ __align__(16) u16 As[128 * 136];
  __shared__ int sidx[128];
  int t = threadIdx.x, row0 = blockIdx.x * 128;
  if (t < 128) sidx[t] = (row0 + t < NV) ? row0 + t : -1;
  __syncthreads();
  f32x4 acc[4][4] = {};
  stage_feat(feat, row0, As);                      // K=64 NiN pass (stride 72 region)
  __syncthreads();
  mma_tile<64>(As, lwt, acc);
  __syncthreads();
  stage_rows<128, 128>(h1, sidx, As);              // K=128 self pass (stride 136)
  __syncthreads();
  mma_tile<128>(As, w2t + 13 * 16384, acc);
  __syncthreads();
  spill_acc(acc, As);
  __syncthreads();
  #pragma unroll
  for (int u = t; u < 2048; u += 256) {
    int r = u >> 4, o = u & 15;
    if (row0 + r < NV)
      *(int4*)(h1 + (long)(row0 + r) * 128 + o * 8) = *(const int4*)(As + r * 136 + o * 8);
  }
}

// ---------- pure gather kernels: 4 lanes per row, all loads in flight, no LDS ----------
// c[32] = self(bf16) + sum of valid partial rows; chain depth = pslot -> partial.
__device__ __forceinline__ void gather_row(int row, int q,
                                           const u16* __restrict__ sp,
                                           const u16* __restrict__ pslot,
                                           const u16* __restrict__ partial,
                                           float c[32]) {
  int4 sv4[4];
  #pragma unroll
  for (int u = 0; u < 4; u++)
    sv4[u] = *(const int4*)((const char*)pslot + (long)row * 64 + u * 16);
  const u16* sv = (const u16*)sv4;
  bf16x8 s0[4];
  #pragma unroll
  for (int u = 0; u < 4; u++) s0[u] = *(const bf16x8*)(sp + (long)row * 128 + q * 32 + u * 8);
  #pragma unroll
  for (int u = 0; u < 4; u++)
    #pragma unroll
    for (int e = 0; e < 8; e++) c[u*8 + e] = bf2f((u16)s0[u][e]);
  #pragma unroll
  for (int k = 0; k < 27; k++) {                   // k compile-time: static sv indexing
    if (k == 13) continue;
    unsigned s = sv[k];
    if (s < CAP) {
      const u16* pr = partial + ((long)k * CAP + s) * 128 + q * 32;
      bf16x8 pv[4];
      #pragma unroll
      for (int u = 0; u < 4; u++) pv[u] = *(const bf16x8*)(pr + u * 8);
      #pragma unroll
      for (int u = 0; u < 4; u++)
        #pragma unroll
        for (int e = 0; e < 8; e++) c[u*8 + e] += bf2f((u16)pv[u][e]);
    }
  }
}

// conv1: h1 = bf16(ReLU(BN2(self + partials)))  -- in place over h1 (self pre-BN)
__global__ __launch_bounds__(256, 4) void k_gather1(const u16* __restrict__ pslot,
                                                    const u16* __restrict__ partial,
                                                    const float* __restrict__ bnp,
                                                    u16* __restrict__ h1) {
  long tid = (long)blockIdx.x * 256 + threadIdx.x;
  int row = (int)(tid >> 2), q = (int)(tid & 3);
  if (row >= NV) return;
  float c[32];
  gather_row(row, q, h1, pslot, partial, c);
  int col0 = q * 32;
  unsigned w[16];
  #pragma unroll
  for (int e = 0; e < 16; e++) {
    float o0 = fmaxf(c[2*e  ] * bnp[col0 + 2*e  ] + bnp[128 + col0 + 2*e  ], 0.f);
    float o1 = fmaxf(c[2*e+1] * bnp[col0 + 2*e+1] + bnp[128 + col0 + 2*e+1], 0.f);
    w[e] = (unsigned)f2bf(o0) | ((unsigned)f2bf(o1) << 16);
  }
  int4* dst = (int4*)(h1 + (long)row * 128 + col0);
  #pragma unroll
  for (int u = 0; u < 4; u++) dst[u] = make_int4(w[4*u], w[4*u+1], w[4*u+2], w[4*u+3]);
}

// conv2: out = f32(self(+NiN) + partials); self rides in h1 (from k_self2)
__global__ __launch_bounds__(256, 4) void k_gather2(const u16* __restrict__ pslot,
                                                    const u16* __restrict__ partial,
                                                    const u16* __restrict__ h1,
                                                    float* __restrict__ out) {
  long tid = (long)blockIdx.x * 256 + threadIdx.x;
  int row = (int)(tid >> 2), q = (int)(tid & 3);
  if (row >= NV) return;
  float c[32];
  gather_row(row, q, h1, pslot, partial, c);
  float* dst = out + (long)row * 128 + q * 32;
  #pragma unroll
  for (int u = 0; u < 8; u++) {
    f32x4 v;
    #pragma unroll
    for (int e = 0; e < 4; e++) v[e] = c[u*4 + e];
    *(f32x4*)(dst + u * 4) = v;
  }
}

extern "C" void kernel_launch(void* const* d_in, const int* in_sizes, int n_in,
                              void* d_out, int out_size, void* d_ws, size_t ws_size,
                              hipStream_t stream) {
  const float* feat = (const float*)d_in[0];
  const int*   pos  = (const int*)d_in[1];
  const float* linw = (const float*)d_in[2];
  const float* g1 = (const float*)d_in[3], *b1 = (const float*)d_in[4];
  const float* m1 = (const float*)d_in[5], *v1 = (const float*)d_in[6];
  const float* W1 = (const float*)d_in[7];
  const float* g2 = (const float*)d_in[8], *b2 = (const float*)d_in[9];
  const float* m2 = (const float*)d_in[10], *v2 = (const float*)d_in[11];
  const float* W2 = (const float*)d_in[12];

  if (ws_size < WS_NEED) return;  // insufficient scratch; fail visibly rather than corrupt

  char* ws = (char*)d_ws;
  u16*   partial = (u16*)(ws + OFF_PART);
  int*   grid    = (int*)(ws + OFF_GRID);          // overlays partial head, dead before it
  int*   pin     = (int*)(ws + OFF_PIN);
  u16*   pslot   = (u16*)(ws + OFF_PSL);
  int*   counts  = (int*)(ws + OFF_CNT);
  u16*   h0      = (u16*)(ws + OFF_H0);
  u16*   h1      = (u16*)(ws + OFF_H1);
  u16*   w1t     = (u16*)(ws + OFF_W1T);
  u16*   w2t     = (u16*)(ws + OFF_W2T);
  u16*   lwt     = (u16*)(ws + OFF_LINW);
  float* bnp     = (float*)(ws + OFF_BNP);
  float* out     = (float*)d_out;

  hipMemsetAsync(grid,  0xFF, (size_t)G3 * 4, stream);       // grid  = -1
  hipMemsetAsync(pslot, 0xFF, (size_t)NV * 32 * 2, stream);  // pslot = 0xFFFF
  hipMemsetAsync(counts, 0, 27 * CPAD * 4, stream);

  k_grid  <<<(NV + 255) / 256, 256, 0, stream>>>(pos, grid);
  k_pairs <<<(NV + 255) / 256, 256, 0, stream>>>(pos, grid, pin, pslot, counts);
  k_bn1   <<<(NV * 16) / 256, 256, 0, stream>>>(feat, g1, b1, m1, v1, h0);
  k_weights<<<56, 256, 0, stream>>>(W1, W2, linw, g2, b2, m2, v2, w1t, w2t, lwt, bnp);

  dim3 gt((NV + 127) / 128);
  dim3 gscat(CAP / 128, 27);
  dim3 gg(((long)NV * 4 + 255) / 256);
  k_scat<64, 64>   <<<gscat, 256, 0, stream>>>(h0, w1t, pin, counts, partial);
  k_self1          <<<gt, 256, 0, stream>>>(h0, w1t, h1);
  k_gather1        <<<gg, 256, 0, stream>>>(pslot, partial, bnp, h1);
  k_scat<128, 128> <<<gscat, 256, 0, stream>>>(h1, w2t, pin, counts, partial);
  k_self2          <<<gt, 256, 0, stream>>>(feat, lwt, h1, w2t);
  k_gather2        <<<gg, 256, 0, stream>>>(pslot, partial, h1, out);
}

// Round 5
// 676.794 us; speedup vs baseline: 1.9503x; 1.1561x over previous
//
#include <hip/hip_runtime.h>

#define G    160
#define G3   (G*G*G)          // 4,096,000
#define NV   300000
#define EPS  1e-4f
#define CAP  24576            // per-tap pair capacity (expected ~21.7k, proven R4-R6)
#define CPAD 32               // counts[k] lives at counts[k*CPAD]: one 128B line per counter
#define PCAP 655360           // total pair capacity (measured ~565k, +16%)
#define TOTIDX 896            // counts[TOTIDX]: global pair allocator (own 128B line)

typedef unsigned short u16;
typedef __attribute__((ext_vector_type(8))) short bf16x8;
typedef __attribute__((ext_vector_type(4))) float f32x4;

// ---- workspace layout (bytes) ----
// R7: CSR-compacted partials. k_pairs allocates each output row a CONTIGUOUS
// segment of partial rows (rowinfo = base<<5|cnt) via block prefix-sum; scat
// writes to pdst[k][slot] (scattered 256B stores, latency-tolerant); gathers
// stream their segments linearly. pslot eliminated.
#define OFF_PART 0ull                          // PCAP*256 = 167,772,160
#define OFF_GRID 0ull                          // 16,384,000 (dies before partial writes)
#define OFF_PIN  167772160ull                  // 27*CAP*4 = 2,654,208
#define OFF_PDST (OFF_PIN  + 2654208ull)       // 27*CAP*4 = 2,654,208
#define OFF_RI   (OFF_PDST + 2654208ull)       // NV*4     = 1,200,000
#define OFF_CNT  (OFF_RI   + 1200000ull)       // 4096
#define OFF_H0   (OFF_CNT  + 4096ull)          // NV*64*2  = 38,400,000
#define OFF_H1   (OFF_H0   + 38400000ull)      // NV*128*2 = 76,800,000
#define OFF_W1T  (OFF_H1   + 76800000ull)      // 27*128*64*2  (B^T layout [k][cout][cin])
#define OFF_W2T  (OFF_W1T  + 442368ull)        // 27*128*128*2
#define OFF_LINW (OFF_W2T  + 884736ull)        // 128*64*2
#define OFF_BNP  (OFF_LINW + 16384ull)         // 2*128*4 (BN2 scale|shift)
#define WS_NEED  (OFF_BNP  + 1024ull)          // ~290.8 MB (< R5's proven 322.7)

__device__ __forceinline__ u16 f2bf(float f) {   // fp32 -> bf16 RNE
  unsigned u = __float_as_uint(f);
  return (u16)((u + 0x7fffu + ((u >> 16) & 1u)) >> 16);
}
__device__ __forceinline__ float bf2f(u16 h) {
  return __uint_as_float(((unsigned)h) << 16);
}

// ---------- phase 1: hash grid + per-tap pair lists + CSR row segments ----------
__global__ void k_grid(const int* __restrict__ pos, int* __restrict__ grid) {
  int i = blockIdx.x * 256 + threadIdx.x;
  if (i < NV)
    grid[(pos[3*i] * G + pos[3*i+1]) * G + pos[3*i+2]] = i;
}

// Per-tap slot allocation (R2-proven LDS-hierarchical) PLUS per-row CSR segment
// allocation: block prefix-sum over per-row valid-tap counts, one global
// atomicAdd per block. rowinfo[i] = (segment_base << 5) | cnt.
__global__ __launch_bounds__(256) void k_pairs(const int* __restrict__ pos,
                        const int* __restrict__ grid,
                        int* __restrict__ pin, int* __restrict__ pdst,
                        int* __restrict__ rowinfo, int* __restrict__ counts) {
  __shared__ int lcnt[27];
  __shared__ int wboff[27][4];
  __shared__ int gbase[27];
  __shared__ int scan[256];
  __shared__ int sgb;
  int t = threadIdx.x, lane = t & 63, wv = t >> 6;
  if (t < 27) lcnt[t] = 0;
  int i = blockIdx.x * 256 + t;
  bool act = (i < NV);
  int p0 = 0, p1 = 1 << 20, p2 = 0;              // inactive threads -> always OOB
  if (act) { p0 = pos[3*i]; p1 = pos[3*i+1]; p2 = pos[3*i+2]; }
  __syncthreads();                               // lcnt zeroed

  int j[26];
  #pragma unroll
  for (int kk = 0; kk < 26; kk++) {              // all 26 loads independent & in flight
    int k = kk < 13 ? kk : kk + 1;
    int q0 = p0 + k/9 - 1, q1 = p1 + (k/3)%3 - 1, q2 = p2 + k%3 - 1;
    bool inb = (q0 >= 0 && q0 < G && q1 >= 0 && q1 < G && q2 >= 0 && q2 < G);
    int addr = inb ? (q0*G + q1)*G + q2 : 0;     // clamped: unconditional load
    int jj = grid[addr];
    j[kk] = inb ? jj : -1;
  }

  unsigned vmask = 0;                            // per-row valid-tap mask (kk order)
  #pragma unroll
  for (int kk = 0; kk < 26; kk++) if (j[kk] >= 0) vmask |= 1u << kk;
  int ci = __popc(vmask);

  unsigned long long m[26];                      // wave-uniform -> SGPRs
  #pragma unroll
  for (int kk = 0; kk < 26; kk++) m[kk] = __ballot(j[kk] >= 0);

  #pragma unroll
  for (int kk = 0; kk < 26; kk++) {              // per-block aggregation in LDS
    int k = kk < 13 ? kk : kk + 1;
    if (lane == 0) wboff[k][wv] = atomicAdd(&lcnt[k], (int)__popcll(m[kk]));
  }
  scan[t] = ci;
  __syncthreads();
  #pragma unroll
  for (int d = 1; d < 256; d <<= 1) {            // Hillis-Steele inclusive scan
    int val = (t >= d) ? scan[t - d] : 0;
    __syncthreads();
    scan[t] += val;
    __syncthreads();
  }
  if (t < 27 && t != 13)                         // 27 concurrent atomics, separate L2 lines
    gbase[t] = atomicAdd(&counts[t * CPAD], lcnt[t]);
  if (t == 255) sgb = atomicAdd(&counts[TOTIDX], scan[255]);
  __syncthreads();

  int rbase = sgb + scan[t] - ci;                // this row's CSR segment base
  int cw = (rbase + ci > PCAP) ? 0 : ci;         // overflow guard (never expected)
  if (act) rowinfo[i] = (rbase << 5) | cw;

  #pragma unroll
  for (int kk = 0; kk < 26; kk++) {
    if (j[kk] >= 0) {
      int k = kk < 13 ? kk : kk + 1;
      int slot = gbase[k] + wboff[k][wv] + (int)__popcll(m[kk] & ((1ull << lane) - 1ull));
      int dst = rbase + __popc(vmask & ((1u << kk) - 1u));
      if (slot < CAP) {
        pin[k*CAP + slot]  = j[kk];
        pdst[k*CAP + slot] = (dst < PCAP) ? dst : -1;
      }
    }
  }
}

// ---------- phase 2: BN1+ReLU -> bf16 h0 ; weight cast/transpose + BN2 precompute ----------
__global__ void k_bn1(const float* __restrict__ feat, const float* g, const float* b,
                      const float* m, const float* v, u16* __restrict__ h0) {
  __shared__ float ss[64], tt[64];
  int t = threadIdx.x;
  if (t < 64) { float s = g[t] * rsqrtf(v[t] + EPS); ss[t] = s; tt[t] = b[t] - m[t]*s; }
  __syncthreads();
  long gt = (long)blockIdx.x * 256 + t;            // one thread per 4 elems
  if (gt >= (long)NV * 16) return;
  int c = (int)(gt & 15) * 4;
  float4 x = ((const float4*)feat)[gt];
  ushort4 q;
  q.x = f2bf(fmaxf(x.x*ss[c  ] + tt[c  ], 0.f));
  q.y = f2bf(fmaxf(x.y*ss[c+1] + tt[c+1], 0.f));
  q.z = f2bf(fmaxf(x.z*ss[c+2] + tt[c+2], 0.f));
  q.w = f2bf(fmaxf(x.w*ss[c+3] + tt[c+3], 0.f));
  ((ushort4*)h0)[gt] = q;
}

// W -> bf16, transposed to [k][cout][cin]; block 55 precomputes BN2 scale/shift.
__global__ void k_weights(const float* __restrict__ W1, const float* __restrict__ W2,
                          const float* __restrict__ linw,
                          const float* __restrict__ g2, const float* __restrict__ b2,
                          const float* __restrict__ m2, const float* __restrict__ v2,
                          u16* __restrict__ w1t, u16* __restrict__ w2t, u16* __restrict__ lwt,
                          float* __restrict__ bnp) {
  __shared__ float tmp[8192];
  int b = blockIdx.x, t = threadIdx.x;
  if (b < 27) {                                    // W1[k]: [64][128] -> [128][64]
    const float* src = W1 + b * 8192;
    u16* dst = w1t + b * 8192;
    for (int u = t; u < 8192; u += 256) tmp[u] = src[u];
    __syncthreads();
    for (int u = t; u < 8192; u += 256) { int c = u >> 6, a = u & 63; dst[c*64 + a] = f2bf(tmp[a*128 + c]); }
  } else if (b < 54) {                             // W2[k]: [128][128] -> [128][128]^T, two halves
    int k = b - 27;
    const float* src = W2 + k * 16384;
    u16* dst = w2t + k * 16384;
    for (int h = 0; h < 2; h++) {
      for (int u = t; u < 8192; u += 256) tmp[u] = src[h*8192 + u];
      __syncthreads();
      for (int u = t; u < 8192; u += 256) { int c = u >> 6, a = u & 63; dst[c*128 + h*64 + a] = f2bf(tmp[a*128 + c]); }
      __syncthreads();
    }
  } else if (b == 54) {                            // lin_w [128][64] is already B^T layout
    for (int u = t; u < 8192; u += 256) lwt[u] = f2bf(linw[u]);
  } else {                                         // BN2 scale|shift
    if (t < 128) { float s = g2[t] * rsqrtf(v2[t] + EPS); bnp[t] = s; bnp[128 + t] = b2[t] - m2[t]*s; }
  }
}

// ---------- GEMM building blocks (128x128 tile, 4 waves, 64x64 quadrants) ----------
template<int K, int RS>   // K: reduce dim; RS: global row stride (bf16 elems)
__device__ __forceinline__ void stage_rows(const u16* __restrict__ src, const int* sidx, u16* lds) {
  const int LPR = K / 8, RPI = 256 / LPR;          // 16B loaders per row, rows per iter
  int t = threadIdx.x, o = t % LPR, r0 = t / LPR;
  #pragma unroll
  for (int r = r0; r < 128; r += RPI) {
    int j = sidx[r];
    int4 val = make_int4(0, 0, 0, 0);
    if (j >= 0) val = *(const int4*)(src + (long)j * RS + o * 8);
    *(int4*)(lds + r * (K + 8) + o * 8) = val;     // +8 elem pad: low-order LDS banking
  }
}

__device__ __forceinline__ void stage_feat(const float* __restrict__ feat, int row0, u16* lds) {
  int t = threadIdx.x, o = t & 15, r0 = t >> 4;    // fp32->bf16 on the fly, K=64
  #pragma unroll
  for (int r = r0; r < 128; r += 16) {
    int row = row0 + r;
    float4 x = make_float4(0.f, 0.f, 0.f, 0.f);
    if (row < NV) x = *(const float4*)(feat + (long)row * 64 + o * 4);
    ushort4 q; q.x = f2bf(x.x); q.y = f2bf(x.y); q.z = f2bf(x.z); q.w = f2bf(x.w);
    *(ushort4*)(lds + r * 72 + o * 4) = q;
  }
}

template<int K>           // A from padded LDS; B-frags straight from L2-hot transposed weights
__device__ __forceinline__ void mma_tile(const u16* As, const u16* __restrict__ wt, f32x4 acc[4][4]) {
  int lane = threadIdx.x & 63, wave = threadIdx.x >> 6;
  int wr = (wave >> 1) * 64, wc = (wave & 1) * 64;
  int lr = lane & 15, lk = (lane >> 4) * 8;
  #pragma unroll
  for (int kk = 0; kk < K; kk += 32) {
    bf16x8 a[4], b[4];
    #pragma unroll
    for (int f = 0; f < 4; f++) a[f] = *(const bf16x8*)(As + (wr + f*16 + lr) * (K + 8) + kk + lk);
    #pragma unroll
    for (int f = 0; f < 4; f++) b[f] = *(const bf16x8*)(wt + (wc + f*16 + lr) * K + kk + lk);
    #pragma unroll
    for (int fr = 0; fr < 4; fr++)
      #pragma unroll
      for (int fc = 0; fc < 4; fc++)
        acc[fr][fc] = __builtin_amdgcn_mfma_f32_16x16x32_bf16(a[fr], b[fc], acc[fr][fc], 0, 0, 0);
  }
}

// Spill f32 acc -> bf16 LDS tile [128][136] (reuses the staging buffer).
__device__ __forceinline__ void spill_acc(const f32x4 acc[4][4], u16* As) {
  int t = threadIdx.x, lane = t & 63, wave = t >> 6;
  int wr = (wave >> 1) * 64, wc = (wave & 1) * 64, cr = (lane >> 4) * 4, cc = lane & 15;
  #pragma unroll
  for (int fr = 0; fr < 4; fr++)
    #pragma unroll
    for (int r = 0; r < 4; r++)
      #pragma unroll
      for (int fc = 0; fc < 4; fc++)
        As[(wr + fr*16 + cr + r) * 136 + wc + fc*16 + cc] = f2bf(acc[fr][fc][r]);
}

// ---------- non-self taps: gather-GEMM -> bf16 partial rows at CSR destinations ----------
template<int K, int RS>
__global__ __launch_bounds__(256, 4) void k_scat(const u16* __restrict__ h, const u16* __restrict__ wt,
                                                 const int* __restrict__ pin,
                                                 const int* __restrict__ pdst,
                                                 const int* __restrict__ counts,
                                                 u16* __restrict__ partial) {
  int k = blockIdx.y;
  int cnt = counts[k * CPAD]; if (cnt > CAP) cnt = CAP;
  int base = blockIdx.x * 128;
  if (base >= cnt) return;                         // k==13 (cnt 0) and tail tiles exit here
  __shared__ __align__(16) u16 As[128 * 136];      // stage: [128][K+8]; epilogue: [128][136]
  __shared__ int sin[128], sdst[128];
  int t = threadIdx.x;
  if (t < 128) sin[t] = (base + t < cnt) ? pin[k*CAP + base + t] : -1;
  else         sdst[t - 128] = (base + t - 128 < cnt) ? pdst[k*CAP + base + t - 128] : -1;
  __syncthreads();
  stage_rows<K, RS>(h, sin, As);
  __syncthreads();
  f32x4 acc[4][4] = {};
  mma_tile<K>(As, wt + k * (K * 128), acc);
  __syncthreads();                                 // As free; reuse as bf16 [128][136]
  spill_acc(acc, As);
  __syncthreads();
  #pragma unroll
  for (int u = t; u < 2048; u += 256) {            // 256B-row stores to CSR destinations
    int r = u >> 4, o = u & 15;
    int d = sdst[r];
    if (d >= 0)
      *(int4*)(partial + (long)d * 128 + o * 8) = *(const int4*)(As + r * 136 + o * 8);
  }
}

// ---------- dense self-tap GEMMs: write bf16 rows into h1 ----------
__global__ __launch_bounds__(256, 4) void k_self1(const u16* __restrict__ h0,
                                                  const u16* __restrict__ w1t,
                                                  u16* __restrict__ h1) {
  __shared__ __align__(16) u16 As[128 * 136];
  __shared__ int sidx[128];
  int t = threadIdx.x, row0 = blockIdx.x * 128;
  if (t < 128) sidx[t] = (row0 + t < NV) ? row0 + t : -1;
  __syncthreads();
  stage_rows<64, 64>(h0, sidx, As);
  __syncthreads();
  f32x4 acc[4][4] = {};
  mma_tile<64>(As, w1t + 13 * 8192, acc);
  __syncthreads();
  spill_acc(acc, As);
  __syncthreads();
  #pragma unroll
  for (int u = t; u < 2048; u += 256) {
    int r = u >> 4, o = u & 15;
    if (row0 + r < NV)
      *(int4*)(h1 + (long)(row0 + r) * 128 + o * 8) = *(const int4*)(As + r * 136 + o * 8);
  }
}

// NiN skip + self tap for conv2; writes bf16 IN PLACE over h1 (own tile staged first).
__global__ __launch_bounds__(256, 4) void k_self2(const float* __restrict__ feat,
                                                  const u16* __restrict__ lwt,
                                                  u16* __restrict__ h1,
                                                  const u16* __restrict__ w2t) {
  __shared__ __align__(16) u16 As[128 * 136];
  __shared__ int sidx[128];
  int t = threadIdx.x, row0 = blockIdx.x * 128;
  if (t < 128) sidx[t] = (row0 + t < NV) ? row0 + t : -1;
  __syncthreads();
  f32x4 acc[4][4] = {};
  stage_feat(feat, row0, As);                      // K=64 NiN pass (stride 72 region)
  __syncthreads();
  mma_tile<64>(As, lwt, acc);
  __syncthreads();
  stage_rows<128, 128>(h1, sidx, As);              // K=128 self pass (stride 136)
  __syncthreads();
  mma_tile<128>(As, w2t + 13 * 16384, acc);
  __syncthreads();
  spill_acc(acc, As);
  __syncthreads();
  #pragma unroll
  for (int u = t; u < 2048; u += 256) {
    int r = u >> 4, o = u & 15;
    if (row0 + r < NV)
      *(int4*)(h1 + (long)(row0 + r) * 128 + o * 8) = *(const int4*)(As + r * 136 + o * 8);
  }
}

// ---------- pure gather kernels: 4 lanes per row, CSR-contiguous partial stream ----------
// c[32] = self(bf16) + sum of cnt CONTIGUOUS partial rows starting at base.
__device__ __forceinline__ void gather_csr(int row, int q, int base, int cnt,
                                           const u16* __restrict__ sp,
                                           const u16* __restrict__ partial,
                                           float c[32]) {
  bf16x8 s0[4];
  const u16* srow = sp + (long)row * 128 + q * 32;
  #pragma unroll
  for (int u = 0; u < 4; u++) s0[u] = *(const bf16x8*)(srow + u * 8);
  #pragma unroll
  for (int u = 0; u < 4; u++)
    #pragma unroll
    for (int e = 0; e < 8; e++) c[u*8 + e] = bf2f((u16)s0[u][e]);
  const u16* pr = partial + (long)base * 128 + q * 32;
  int p = 0;
  for (; p + 2 <= cnt; p += 2) {                   // 2-wide: 8 independent 16B loads in flight
    bf16x8 a[4], b[4];
    #pragma unroll
    for (int u = 0; u < 4; u++) a[u] = *(const bf16x8*)(pr + u * 8);
    #pragma unroll
    for (int u = 0; u < 4; u++) b[u] = *(const bf16x8*)(pr + 128 + u * 8);
    #pragma unroll
    for (int u = 0; u < 4; u++)
      #pragma unroll
      for (int e = 0; e < 8; e++) c[u*8 + e] += bf2f((u16)a[u][e]) + bf2f((u16)b[u][e]);
    pr += 256;
  }
  if (p < cnt) {
    bf16x8 a[4];
    #pragma unroll
    for (int u = 0; u < 4; u++) a[u] = *(const bf16x8*)(pr + u * 8);
    #pragma unroll
    for (int u = 0; u < 4; u++)
      #pragma unroll
      for (int e = 0; e < 8; e++) c[u*8 + e] += bf2f((u16)a[u][e]);
  }
}

// conv1: h1 = bf16(ReLU(BN2(self + partials)))  -- in place over h1 (self pre-BN)
__global__ __launch_bounds__(256) void k_gather1(const int* __restrict__ rowinfo,
                                                 const u16* __restrict__ partial,
                                                 const float* __restrict__ bnp,
                                                 u16* __restrict__ h1) {
  long tid = (long)blockIdx.x * 256 + threadIdx.x;
  int row = (int)(tid >> 2), q = (int)(tid & 3);
  if (row >= NV) return;
  int ri = rowinfo[row];
  int base = (int)((unsigned)ri >> 5), cnt = ri & 31;
  float c[32];
  gather_csr(row, q, base, cnt, h1, partial, c);
  int col0 = q * 32;
  unsigned w[16];
  #pragma unroll
  for (int e = 0; e < 16; e++) {
    float o0 = fmaxf(c[2*e  ] * bnp[col0 + 2*e  ] + bnp[128 + col0 + 2*e  ], 0.f);
    float o1 = fmaxf(c[2*e+1] * bnp[col0 + 2*e+1] + bnp[128 + col0 + 2*e+1], 0.f);
    w[e] = (unsigned)f2bf(o0) | ((unsigned)f2bf(o1) << 16);
  }
  int4* dst = (int4*)(h1 + (long)row * 128 + col0);
  #pragma unroll
  for (int u = 0; u < 4; u++) dst[u] = make_int4(w[4*u], w[4*u+1], w[4*u+2], w[4*u+3]);
}

// conv2: out = f32(self(+NiN) + partials); self rides in h1 (from k_self2)
__global__ __launch_bounds__(256) void k_gather2(const int* __restrict__ rowinfo,
                                                 const u16* __restrict__ partial,
                                                 const u16* __restrict__ h1,
                                                 float* __restrict__ out) {
  long tid = (long)blockIdx.x * 256 + threadIdx.x;
  int row = (int)(tid >> 2), q = (int)(tid & 3);
  if (row >= NV) return;
  int ri = rowinfo[row];
  int base = (int)((unsigned)ri >> 5), cnt = ri & 31;
  float c[32];
  gather_csr(row, q, base, cnt, h1, partial, c);
  float* dst = out + (long)row * 128 + q * 32;
  #pragma unroll
  for (int u = 0; u < 8; u++) {
    f32x4 v;
    #pragma unroll
    for (int e = 0; e < 4; e++) v[e] = c[u*4 + e];
    *(f32x4*)(dst + u * 4) = v;
  }
}

extern "C" void kernel_launch(void* const* d_in, const int* in_sizes, int n_in,
                              void* d_out, int out_size, void* d_ws, size_t ws_size,
                              hipStream_t stream) {
  const float* feat = (const float*)d_in[0];
  const int*   pos  = (const int*)d_in[1];
  const float* linw = (const float*)d_in[2];
  const float* g1 = (const float*)d_in[3], *b1 = (const float*)d_in[4];
  const float* m1 = (const float*)d_in[5], *v1 = (const float*)d_in[6];
  const float* W1 = (const float*)d_in[7];
  const float* g2 = (const float*)d_in[8], *b2 = (const float*)d_in[9];
  const float* m2 = (const float*)d_in[10], *v2 = (const float*)d_in[11];
  const float* W2 = (const float*)d_in[12];

  if (ws_size < WS_NEED) return;  // insufficient scratch; fail visibly rather than corrupt

  char* ws = (char*)d_ws;
  u16*   partial = (u16*)(ws + OFF_PART);
  int*   grid    = (int*)(ws + OFF_GRID);          // overlays partial head, dead before it
  int*   pin     = (int*)(ws + OFF_PIN);
  int*   pdst    = (int*)(ws + OFF_PDST);
  int*   rowinfo = (int*)(ws + OFF_RI);
  int*   counts  = (int*)(ws + OFF_CNT);
  u16*   h0      = (u16*)(ws + OFF_H0);
  u16*   h1      = (u16*)(ws + OFF_H1);
  u16*   w1t     = (u16*)(ws + OFF_W1T);
  u16*   w2t     = (u16*)(ws + OFF_W2T);
  u16*   lwt     = (u16*)(ws + OFF_LINW);
  float* bnp     = (float*)(ws + OFF_BNP);
  float* out     = (float*)d_out;

  hipMemsetAsync(grid,  0xFF, (size_t)G3 * 4, stream);       // grid = -1
  hipMemsetAsync(counts, 0, 4096, stream);                   // per-tap + total allocators

  k_grid  <<<(NV + 255) / 256, 256, 0, stream>>>(pos, grid);
  k_pairs <<<(NV + 255) / 256, 256, 0, stream>>>(pos, grid, pin, pdst, rowinfo, counts);
  k_bn1   <<<(NV * 16) / 256, 256, 0, stream>>>(feat, g1, b1, m1, v1, h0);
  k_weights<<<56, 256, 0, stream>>>(W1, W2, linw, g2, b2, m2, v2, w1t, w2t, lwt, bnp);

  dim3 gt((NV + 127) / 128);
  dim3 gscat(CAP / 128, 27);
  dim3 gg(((long)NV * 4 + 255) / 256);
  k_scat<64, 64>   <<<gscat, 256, 0, stream>>>(h0, w1t, pin, pdst, counts, partial);
  k_self1          <<<gt, 256, 0, stream>>>(h0, w1t, h1);
  k_gather1        <<<gg, 256, 0, stream>>>(rowinfo, partial, bnp, h1);
  k_scat<128, 128> <<<gscat, 256, 0, stream>>>(h1, w2t, pin, pdst, counts, partial);
  k_self2          <<<gt, 256, 0, stream>>>(feat, lwt, h1, w2t);
  k_gather2        <<<gg, 256, 0, stream>>>(rowinfo, partial, h1, out);
}